// Round 13
// baseline (969.986 us; speedup 1.0000x reference)
//
#include <hip/hip_runtime.h>

#define BB 16
#define NN 1024
#define LDT 16384          // column count of all transposed feature buffers

typedef float4 f4;
typedef __attribute__((ext_vector_type(8))) short bf16x8;
typedef __attribute__((ext_vector_type(4))) float f32x4;

// bf16 pack/unpack (RNE)
__device__ __forceinline__ unsigned f2b1(float f) {
    unsigned u = __builtin_bit_cast(unsigned, f);
    return (u + 0x7fffu + ((u >> 16) & 1u)) >> 16;
}
__device__ __forceinline__ float b2f1(unsigned s) {
    unsigned u = (s & 0xffffu) << 16;
    return __builtin_bit_cast(float, u);
}

// LDS tile element offset, swizzled. Tile is [row][k] = [R][64] shorts.
// g = (row&7) ^ ((row>>3)&7): conflict-free for transpose-writes, row-copies and
// fragment reads, with compile-time register indexing everywhere.
#define SW(r, k) ((r) * 64 + ((k) ^ (((((r) & 7) ^ (((r) >> 3) & 7))) << 3)))

// ---- async global->LDS, 16B per lane. LDS dest = wave-uniform base + lane*16
// (linear); the global source chunk is pre-swizzled so data lands at SW(r,k):
// segment s covers rows 8s..8s+7; lane l -> row 8s+(l>>3), holds chunk
// jc = (l&7) ^ (l>>3) ^ (s&7) (== SW's placement). Reads stay unchanged.
__device__ __forceinline__ void gload16(const unsigned short* g, short* l) {
    __builtin_amdgcn_global_load_lds(
        (const __attribute__((address_space(1))) unsigned int*)g,
        (__attribute__((address_space(3))) unsigned int*)l, 16, 0, 0);
}

__device__ __forceinline__ float wave_sum(float v) {
    #pragma unroll
    for (int m = 32; m >= 1; m >>= 1) v += __shfl_xor(v, m);
    return v;
}
__device__ __forceinline__ float wave_max(float v) {
    #pragma unroll
    for (int m = 32; m >= 1; m >>= 1) v = fmaxf(v, __shfl_xor(v, m));
    return v;
}

// ---- transpose staging (pair-pack): T[r=0..127][c=0..63] = src[(c0+c)*LDT + col_base + r] ----
__device__ __forceinline__ void stage_tr(short* T, const unsigned short* src,
                                         size_t col_base, int c0, int Cvalid, int tid) {
    #pragma unroll
    for (int n = 0; n < 2; n++) {
        int q = n * 256 + tid;
        int p = q >> 4, h = q & 15;
        int cg = c0 + 2 * p;
        uint4 r0 = make_uint4(0, 0, 0, 0), r1 = make_uint4(0, 0, 0, 0);
        if (cg < Cvalid)     r0 = *(const uint4*)&src[(size_t)cg * LDT + col_base + 8 * h];
        if (cg + 1 < Cvalid) r1 = *(const uint4*)&src[(size_t)(cg + 1) * LDT + col_base + 8 * h];
        const unsigned* a0 = (const unsigned*)&r0;
        const unsigned* a1 = (const unsigned*)&r1;
        #pragma unroll
        for (int e = 0; e < 8; e++) {
            unsigned lo = (e & 1) ? (a0[e >> 1] >> 16) : (a0[e >> 1] & 0xffffu);
            unsigned hi = (e & 1) ? (a1[e >> 1] >> 16) : (a1[e >> 1] & 0xffffu);
            int r = 8 * h + e;
            *(unsigned*)&T[SW(r, 2 * p)] = lo | (hi << 16);
        }
    }
}

// ================= input prep =================
__global__ void xt_prep_kernel(const float* __restrict__ x, short* __restrict__ xh,
                               short* __restrict__ xl) {
    int m = blockIdx.x * 256 + threadIdx.x;
    #pragma unroll
    for (int c = 0; c < 8; c++) {
        float v = (c < 6) ? x[(size_t)m * 6 + c] : 0.f;
        unsigned h = f2b1(v);
        unsigned l = f2b1(v - b2f1(h));
        xh[(size_t)c * LDT + m] = (short)h;
        xl[(size_t)c * LDT + m] = (short)l;
    }
}

__global__ void wtt_prep_kernel(const float* __restrict__ Wk, short* __restrict__ WtT,
                                int Kp64, int KpValid, int CpadM1, int shift, int Cin, int Cout) {
    int idx = blockIdx.x * 256 + threadIdx.x;
    if (idx >= Cout * Kp64) return;
    int co = idx / Kp64, kk = idx - co * Kp64;
    int c = kk & CpadM1;
    float val = 0.f;
    if (kk < KpValid && c < Cin)
        val = Wk[((size_t)(kk >> shift) * Cin + c) * Cout + co];
    WtT[(size_t)co * Kp64 + kk] = (short)f2b1(val);
}

// ---- FC weight transpose: WtT[o][k] = Wt[k][o] ----
__global__ void wtrans_kernel(const float* __restrict__ Wt, float* __restrict__ WtT,
                              int K, int O) {
    int idx = blockIdx.x * 256 + threadIdx.x;
    if (idx >= K * O) return;
    int o = idx / K, k = idx - o * K;
    WtT[idx] = Wt[(size_t)k * O + o];
}

// ---- scaled copy: dst[c][m] = bf16( src[c][m] * coeff[m] ) ----
__global__ void scale_sc_kernel(const short* __restrict__ src, const float* __restrict__ coeff,
                                short* __restrict__ dst, int total8) {
    int q = blockIdx.x * 256 + threadIdx.x;
    if (q >= total8) return;
    size_t base = (size_t)q * 8;
    int m8 = (int)(base & (LDT - 1));
    uint4 v = *(const uint4*)&((const unsigned short*)src)[base];
    f4 c0 = *(const f4*)&coeff[m8];
    f4 c1 = *(const f4*)&coeff[m8 + 4];
    const float* cp0 = (const float*)&c0;
    const float* cp1 = (const float*)&c1;
    unsigned* vp = (unsigned*)&v;
    #pragma unroll
    for (int e = 0; e < 4; e++) {
        float se0 = (e < 2) ? cp0[2 * e] : cp1[2 * e - 4];
        float se1 = (e < 2) ? cp0[2 * e + 1] : cp1[2 * e - 3];
        vp[e] = f2b1(b2f1(vp[e]) * se0) | (f2b1(b2f1(vp[e] >> 16) * se1) << 16);
    }
    *(uint4*)&((unsigned short*)dst)[base] = v;
}

// ---- layer-wide transpose: XR[m][c] = XT[c][m], rows padded/zeroed to CR ----
__global__ __launch_bounds__(256)
void xpose_kernel(const short* __restrict__ H, const short* __restrict__ L,
                  int Cvalid, int CR, short* __restrict__ XRh, short* __restrict__ XRl) {
    __shared__ short Th[128 * 64], Tl[128 * 64];
    int tid = threadIdx.x;
    int m0 = blockIdx.x * 128, c0 = blockIdx.y * 64;
    stage_tr(Th, (const unsigned short*)H, m0, c0, Cvalid, tid);
    stage_tr(Tl, (const unsigned short*)L, m0, c0, Cvalid, tid);
    __syncthreads();
    #pragma unroll
    for (int n = 0; n < 4; n++) {
        int q = n * 256 + tid;
        int r = q >> 3, j = q & 7;
        int g = (r & 7) ^ ((r >> 3) & 7);
        *(uint4*)&XRh[(size_t)(m0 + r) * CR + c0 + 8 * j] = *(const uint4*)&Th[r * 64 + 8 * (j ^ g)];
        *(uint4*)&XRl[(size_t)(m0 + r) * CR + c0 + 8 * j] = *(const uint4*)&Tl[r * 64 + 8 * (j ^ g)];
    }
}

// ================= squared norms from hi/lo (partial over 128-c chunks) =================
__global__ void sqt_part_kernel(const short* __restrict__ H, const short* __restrict__ L,
                                int C, float* __restrict__ dst) {
    int m = blockIdx.x * 256 + threadIdx.x;
    int cb = blockIdx.y * 128;
    int ce = min(cb + 128, C);
    const unsigned short* Hp = (const unsigned short*)H;
    const unsigned short* Lp = (const unsigned short*)L;
    float s = 0.f;
    for (int c = cb; c < ce; c++) {
        float v = b2f1(Hp[(size_t)c * LDT + m]) + b2f1(Lp[(size_t)c * LDT + m]);
        s += v * v;
    }
    dst[(size_t)blockIdx.y * LDT + m] = s;
}
__global__ void sqt_red_kernel(const float* __restrict__ part, int NC, float* __restrict__ sq) {
    int m = blockIdx.x * 256 + threadIdx.x;
    float s = 0.f;
    for (int y = 0; y < NC; y++) s += part[(size_t)y * LDT + m];
    sq[m] = s;
}

// ====== adjacency + fused row-sum partials: W[b][j][i] = exp(2G - sq_i - sq_j) ======
// 4 waves; wave tile 64(j) x 64(i). Staging via global_load_lds from row-major XR.
// Off-diag partial sums -> Wpart; diag -> diagW.
__global__ __launch_bounds__(256)
void adj_mfma_kernel(const short* __restrict__ XRh, const short* __restrict__ XRl,
                     int ck64, int CR, const float* __restrict__ sq,
                     short* __restrict__ Wb, float* __restrict__ Wpart,
                     float* __restrict__ diagW) {
    __shared__ short Ah[128 * 64], Al[128 * 64], Bh[128 * 64], Bl[128 * 64];
    __shared__ float jpart[128][2];
    int tid = threadIdx.x, lane = tid & 63, w = tid >> 6;
    int wj = w >> 1, wi = w & 1;
    int b = blockIdx.z, i0 = blockIdx.x * 128, j0 = blockIdx.y * 128;
    size_t bo = (size_t)b * NN;
    f32x4 acc[4][4] = {};
    const unsigned short* Hp = (const unsigned short*)XRh;
    const unsigned short* Lp = (const unsigned short*)XRl;
    // per-lane pre-swizzled source offsets for the 4 segments this wave stages per tile
    int rr = lane >> 3, jj = lane & 7;
    size_t offI[4], offJ[4];
    #pragma unroll
    for (int m = 0; m < 4; m++) {
        int s = w + m * 4;
        int jc = jj ^ rr ^ (s & 7);
        offI[m] = (size_t)(bo + i0 + 8 * s + rr) * CR + 8 * jc;
        offJ[m] = (size_t)(bo + j0 + 8 * s + rr) * CR + 8 * jc;
    }
    for (int t = 0; t < ck64; t++) {
        int c0 = t * 64;
        #pragma unroll
        for (int m = 0; m < 4; m++) {
            int s512 = (w + m * 4) * 512;
            gload16(Hp + offI[m] + c0, Ah + s512);
            gload16(Lp + offI[m] + c0, Al + s512);
            gload16(Hp + offJ[m] + c0, Bh + s512);
            gload16(Lp + offJ[m] + c0, Bl + s512);
        }
        __syncthreads();
        int la = lane & 15;
        #pragma unroll
        for (int ks = 0; ks < 2; ks++) {
            int kb = ks * 32 + (lane >> 4) * 8;
            bf16x8 jh[4], jl[4], ih[4], il[4];
            #pragma unroll
            for (int f = 0; f < 4; f++) {
                int jr = wj * 64 + f * 16 + la;
                jh[f] = *(const bf16x8*)&Bh[SW(jr, kb)];
                jl[f] = *(const bf16x8*)&Bl[SW(jr, kb)];
                int ir = wi * 64 + f * 16 + la;
                ih[f] = *(const bf16x8*)&Ah[SW(ir, kb)];
                il[f] = *(const bf16x8*)&Al[SW(ir, kb)];
            }
            #pragma unroll
            for (int fq = 0; fq < 4; fq++)
                #pragma unroll
                for (int fi = 0; fi < 4; fi++) {
                    acc[fq][fi] = __builtin_amdgcn_mfma_f32_16x16x32_bf16(jh[fq], ih[fi], acc[fq][fi], 0, 0, 0);
                    acc[fq][fi] = __builtin_amdgcn_mfma_f32_16x16x32_bf16(jh[fq], il[fi], acc[fq][fi], 0, 0, 0);
                    acc[fq][fi] = __builtin_amdgcn_mfma_f32_16x16x32_bf16(jl[fq], ih[fi], acc[fq][fi], 0, 0, 0);
                }
        }
        __syncthreads();
    }
    const float* sqb = sq + bo;
    unsigned short* Wout = (unsigned short*)Wb + bo * NN;
    float si_[4];
    int iloc[4];
    #pragma unroll
    for (int fi = 0; fi < 4; fi++) {
        iloc[fi] = i0 + wi * 64 + fi * 16 + (lane & 15);
        si_[fi] = sqb[iloc[fi]];
    }
    #pragma unroll
    for (int fq = 0; fq < 4; fq++) {
        int jb = j0 + wj * 64 + fq * 16 + (lane >> 4) * 4;
        #pragma unroll
        for (int r = 0; r < 4; r++) {
            int j = jb + r;
            float sj = sqb[j];
            float p = 0.f;
            #pragma unroll
            for (int fi = 0; fi < 4; fi++) {
                float val = __expf(2.f * ((const float*)&acc[fq][fi])[r] - si_[fi] - sj);
                Wout[(size_t)j * NN + iloc[fi]] = (unsigned short)f2b1(val);
                if (iloc[fi] == j) diagW[bo + j] = val;
                else p += val;
            }
            p += __shfl_xor(p, 1); p += __shfl_xor(p, 2);
            p += __shfl_xor(p, 4); p += __shfl_xor(p, 8);
            if ((lane & 15) == 0)
                jpart[wj * 64 + fq * 16 + (lane >> 4) * 4 + r][wi] = p;
        }
    }
    __syncthreads();
    if (tid < 128)
        Wpart[(size_t)blockIdx.x * (BB * NN) + bo + j0 + tid] = jpart[tid][0] + jpart[tid][1];
}

// ====== reduce partials -> coefficient vectors ======
__global__ void reduce_prep_kernel(const float* __restrict__ Wpart, const float* __restrict__ diagW,
                                   float* dinv, float* dinvP, float* cA1, float* cA2, float* cAV) {
    int idx = blockIdx.x * 256 + threadIdx.x;    // [0, 16384)
    float s = 0.f;
    #pragma unroll
    for (int x = 0; x < 8; x++) s += Wpart[(size_t)x * (BB * NN) + idx];
    float d = diagW[idx];
    float dv = rsqrtf(s + d);    // full sum (incl diag)
    float dp = rsqrtf(s);        // exact off-diag sum (no cancellation)
    dinv[idx] = dv; dinvP[idx] = dp;
    cA1[idx] = -dv; cA2[idx] = -2.f * dv; cAV[idx] = -dp;
}

// ====== W-GEMM (8 waves): Dst[c][i] = cA_i * sum_j W[i][j]*Bsc[c][j] (+ prevSign*Prev[c][i]) ======
// Staging via global_load_lds (linear LDS dest, pre-swizzled global chunk).
// XB = i-tile rows (128 or 64). XB=64 doubles the grid for small-C launches.
template<bool HAS_PREV, bool SKIP_DIAG, bool WRITE_SC, int XB>
__global__ __launch_bounds__(512)
void wgemm2_kernel(const short* __restrict__ W, const short* __restrict__ Bsc,
                   const float* __restrict__ cAvec, float prevSign,
                   const short* __restrict__ PrevT, const float* __restrict__ scVec,
                   short* __restrict__ DstT, short* __restrict__ DstSc, int Cvalid) {
    __shared__ short As[XB * 64], Bs[128 * 64];
    constexpr int NFI = XB / 64;                 // i-frags per wave (2 or 1)
    int tid = threadIdx.x, lane = tid & 63, w = tid >> 6;
    int wcc = w >> 2, wii = w & 3;               // wave tile: 64 c x XB/4 i
    int b = blockIdx.z, i0 = blockIdx.x * XB, c0 = blockIdx.y * 128;
    size_t bo = (size_t)b * NN;
    const unsigned short* Wp = (const unsigned short*)W + bo * NN;
    const unsigned short* Bp = (const unsigned short*)Bsc;
    int rr = lane >> 3, jj = lane & 7;
    int jc = jj ^ rr ^ (w & 7);                  // (w+8)&7 == w&7
    const unsigned short* aR0 = Wp + (size_t)(i0 + 8 * w + rr) * NN + 8 * jc;
    const unsigned short* aR1 = Wp + (size_t)(i0 + 8 * ((XB == 128) ? w + 8 : w) + rr) * NN + 8 * jc;
    const unsigned short* bR0 = Bp + (size_t)(c0 + 8 * w + rr) * LDT + bo + 8 * jc;
    const unsigned short* bR1 = Bp + (size_t)(c0 + 8 * (w + 8) + rr) * LDT + bo + 8 * jc;
    short* aL0 = As + w * 512;
    short* aL1 = As + ((XB == 128) ? w + 8 : w) * 512;
    short* bL0 = Bs + w * 512; short* bL1 = Bs + (w + 8) * 512;
    f32x4 acc[4][NFI] = {};
    for (int k0 = 0; k0 < NN; k0 += 64) {
        gload16(aR0 + k0, aL0);
        if (XB == 128) gload16(aR1 + k0, aL1);
        gload16(bR0 + k0, bL0);
        gload16(bR1 + k0, bL1);
        __syncthreads();                          // compiler drains vmcnt before barrier
        if (SKIP_DIAG) {
            if (k0 >= i0 && k0 < i0 + XB) {       // diag band intersects this k-tile
                if (tid < 64) As[SW((k0 - i0) + tid, tid)] = 0;
                __syncthreads();
            }
        }
        int la = lane & 15;
        #pragma unroll
        for (int ks = 0; ks < 2; ks++) {
            int kb = ks * 32 + (lane >> 4) * 8;
            bf16x8 ac[4], bi[NFI];
            #pragma unroll
            for (int f = 0; f < 4; f++) ac[f] = *(const bf16x8*)&Bs[SW(wcc * 64 + f * 16 + la, kb)];
            #pragma unroll
            for (int f = 0; f < NFI; f++) bi[f] = *(const bf16x8*)&As[SW(wii * (XB / 4) + f * 16 + la, kb)];
            #pragma unroll
            for (int fq = 0; fq < 4; fq++)
                #pragma unroll
                for (int fi = 0; fi < NFI; fi++)
                    acc[fq][fi] = __builtin_amdgcn_mfma_f32_16x16x32_bf16(ac[fq], bi[fi], acc[fq][fi], 0, 0, 0);
        }
        __syncthreads();
    }
    const unsigned short* Pp = (const unsigned short*)PrevT;
    unsigned short* Dp = (unsigned short*)DstT;
    unsigned short* Sp = (unsigned short*)DstSc;
    #pragma unroll
    for (int fi = 0; fi < NFI; fi++) {
        int i = i0 + wii * (XB / 4) + fi * 16 + (lane & 15);
        float ca = cAvec[bo + i];
        float sc = WRITE_SC ? scVec[bo + i] : 0.f;
        #pragma unroll
        for (int fq = 0; fq < 4; fq++) {
            int cb = c0 + wcc * 64 + fq * 16 + (lane >> 4) * 4;
            const float* av = (const float*)&acc[fq][fi];
            #pragma unroll
            for (int r = 0; r < 4; r++) {
                int c = cb + r;
                if (c < Cvalid) {
                    float v = ca * av[r];
                    if (HAS_PREV) v += prevSign * b2f1(Pp[(size_t)c * LDT + bo + i]);
                    Dp[(size_t)c * LDT + bo + i] = (unsigned short)f2b1(v);
                    if (WRITE_SC) Sp[(size_t)c * LDT + bo + i] = (unsigned short)f2b1(v * sc);
                }
            }
        }
    }
}

// ====== feature GEMM (8 waves): Out[co][m] = relu(sum_kk Zcat[m][kk]*Wt[kk][co] + bias) ======
// B staged via global_load_lds; A-transpose loads software-pipelined. Also emits
// the dinvP-scaled output (OutS = relu_out * scV[m]) used by the V-step,
// replacing the separate scale pass.
__global__ __launch_bounds__(512)
void fgemm_mfma_kernel(const short* __restrict__ A0T, const short* __restrict__ ZrT,
                       const short* __restrict__ WtT, int Kp64, int KpValid, int Cpad,
                       const float* __restrict__ bias, const float* __restrict__ scV,
                       short* __restrict__ OutH, short* __restrict__ OutL,
                       short* __restrict__ OutS) {
    __shared__ short As[128 * 64], Bs[128 * 64];
    int tid = threadIdx.x, lane = tid & 63, w = tid >> 6;
    int wco = w >> 2, wm = w & 3;                // wave tile: 64 co x 32 m
    int m0 = blockIdx.x * 128, co0 = blockIdx.y * 128;
    const unsigned short* A0 = (const unsigned short*)A0T;
    const unsigned short* Zr = (const unsigned short*)ZrT;
    const unsigned short* Wt = (const unsigned short*)WtT;
    // B staging addresses (gload16, row stride Kp64)
    int rr = lane >> 3, jj = lane & 7;
    int jcB = jj ^ rr ^ (w & 7);
    const unsigned short* bB0 = Wt + (size_t)(co0 + 8 * w + rr) * Kp64 + 8 * jcB;
    const unsigned short* bB1 = Wt + (size_t)(co0 + 8 * (w + 8) + rr) * Kp64 + 8 * jcB;
    short* bL0 = Bs + w * 512; short* bL1 = Bs + (w + 8) * 512;
    int p = tid >> 4, h = tid & 15;
    uint4 ra0, ra1;
    auto loadA = [&](int kk0) {
        int kg0 = kk0 + 2 * p;
        ra0 = make_uint4(0, 0, 0, 0); ra1 = make_uint4(0, 0, 0, 0);
        if (kg0 < KpValid) {
            const unsigned short* s0 = (kg0 < Cpad) ? (A0 + (size_t)kg0 * LDT)
                                                    : (Zr + (size_t)(kg0 - Cpad) * LDT);
            ra0 = *(const uint4*)&s0[m0 + 8 * h];
        }
        if (kg0 + 1 < KpValid) {
            int kg1 = kg0 + 1;
            const unsigned short* s1 = (kg1 < Cpad) ? (A0 + (size_t)kg1 * LDT)
                                                    : (Zr + (size_t)(kg1 - Cpad) * LDT);
            ra1 = *(const uint4*)&s1[m0 + 8 * h];
        }
    };
    f32x4 acc[4][2] = {};
    loadA(0);
    for (int kk0 = 0; kk0 < Kp64; kk0 += 64) {
        {   // unpack held A regs (tile kk0) -> LDS, compile-time e indexing
            const unsigned* a0 = (const unsigned*)&ra0;
            const unsigned* a1 = (const unsigned*)&ra1;
            #pragma unroll
            for (int e = 0; e < 8; e++) {
                unsigned lo = (e & 1) ? (a0[e >> 1] >> 16) : (a0[e >> 1] & 0xffffu);
                unsigned hi = (e & 1) ? (a1[e >> 1] >> 16) : (a1[e >> 1] & 0xffffu);
                *(unsigned*)&As[SW(8 * h + e, 2 * p)] = lo | (hi << 16);
            }
        }
        gload16(bB0 + kk0, bL0);                 // B: weight rows, async DMA
        gload16(bB1 + kk0, bL1);
        __syncthreads();
        if (kk0 + 64 < Kp64) loadA(kk0 + 64);    // issue next A loads under MFMAs
        int la = lane & 15;
        #pragma unroll
        for (int ks = 0; ks < 2; ks++) {
            int kb = ks * 32 + (lane >> 4) * 8;
            bf16x8 ac[4], bm[2];
            #pragma unroll
            for (int f = 0; f < 4; f++) ac[f] = *(const bf16x8*)&Bs[SW(wco * 64 + f * 16 + la, kb)];
            #pragma unroll
            for (int f = 0; f < 2; f++) bm[f] = *(const bf16x8*)&As[SW(wm * 32 + f * 16 + la, kb)];
            #pragma unroll
            for (int fq = 0; fq < 4; fq++)
                #pragma unroll
                for (int fi = 0; fi < 2; fi++)
                    acc[fq][fi] = __builtin_amdgcn_mfma_f32_16x16x32_bf16(ac[fq], bm[fi], acc[fq][fi], 0, 0, 0);
        }
        __syncthreads();
    }
    unsigned short* OH = (unsigned short*)OutH;
    unsigned short* OL = (unsigned short*)OutL;
    unsigned short* OS = (unsigned short*)OutS;
    #pragma unroll
    for (int fi = 0; fi < 2; fi++) {
        int m = m0 + wm * 32 + fi * 16 + (lane & 15);
        float sc = scV[m];
        #pragma unroll
        for (int fq = 0; fq < 4; fq++) {
            int cb = co0 + wco * 64 + fq * 16 + (lane >> 4) * 4;
            const float* av = (const float*)&acc[fq][fi];
            #pragma unroll
            for (int r = 0; r < 4; r++) {
                int co = cb + r;
                float v = av[r] + bias[co];
                v = v > 0.f ? v : 0.f;
                unsigned ph = f2b1(v);
                unsigned pl = f2b1(v - b2f1(ph));
                OH[(size_t)co * LDT + m] = (unsigned short)ph;
                OL[(size_t)co * LDT + m] = (unsigned short)pl;
                OS[(size_t)co * LDT + m] = (unsigned short)f2b1(v * sc);
            }
        }
    }
}

// ====== M partials: Mpart[z][cj][ci] = sum_{m in chunk} XT[ci][m]*VT[cj][m] ======
__global__ __launch_bounds__(256)
void mgemm_mfma_kernel(const short* __restrict__ XT, const short* __restrict__ VT,
                       float* __restrict__ Mpart, int Cout, int kChunk) {
    __shared__ short As[128 * 64], Bs[128 * 64];
    int tid = threadIdx.x, lane = tid & 63, w = tid >> 6;
    int wcj = w >> 1, wci = w & 1;
    int ci0 = blockIdx.x * 128, cj0 = blockIdx.y * 128;
    int kStart = blockIdx.z * kChunk;
    const unsigned short* Xp = (const unsigned short*)XT + (size_t)ci0 * LDT;
    const unsigned short* Vp = (const unsigned short*)VT + (size_t)cj0 * LDT;
    // hoisted per-lane source addresses: 4 waves x 4 segments each
    int rr = lane >> 3, jj = lane & 7;
    const unsigned short* aB[4];
    const unsigned short* bB[4];
    short* aL[4]; short* bL[4];
    #pragma unroll
    for (int n = 0; n < 4; n++) {
        int s = w + n * 4;
        int jc = jj ^ rr ^ (s & 7);
        aB[n] = Xp + (size_t)(8 * s + rr) * LDT + 8 * jc;
        bB[n] = Vp + (size_t)(8 * s + rr) * LDT + 8 * jc;
        aL[n] = As + s * 512; bL[n] = Bs + s * 512;
    }
    f32x4 acc[4][4] = {};
    for (int k0 = kStart; k0 < kStart + kChunk; k0 += 64) {
        #pragma unroll
        for (int n = 0; n < 4; n++) {
            gload16(aB[n] + k0, aL[n]);
            gload16(bB[n] + k0, bL[n]);
        }
        __syncthreads();
        int la = lane & 15;
        #pragma unroll
        for (int ks = 0; ks < 2; ks++) {
            int kb = ks * 32 + (lane >> 4) * 8;
            bf16x8 aj[4], bi[4];
            #pragma unroll
            for (int f = 0; f < 4; f++) {
                aj[f] = *(const bf16x8*)&Bs[SW(wcj * 64 + f * 16 + la, kb)];   // cj frags
                bi[f] = *(const bf16x8*)&As[SW(wci * 64 + f * 16 + la, kb)];   // ci frags
            }
            #pragma unroll
            for (int fq = 0; fq < 4; fq++)
                #pragma unroll
                for (int fi = 0; fi < 4; fi++)
                    acc[fq][fi] = __builtin_amdgcn_mfma_f32_16x16x32_bf16(aj[fq], bi[fi], acc[fq][fi], 0, 0, 0);
        }
        __syncthreads();
    }
    float* pt = Mpart + (size_t)blockIdx.z * Cout * Cout;
    #pragma unroll
    for (int fq = 0; fq < 4; fq++) {
        int cjb = cj0 + wcj * 64 + fq * 16 + (lane >> 4) * 4;
        #pragma unroll
        for (int fi = 0; fi < 4; fi++) {
            int ci = ci0 + wci * 64 + fi * 16 + (lane & 15);
            const float* av = (const float*)&acc[fq][fi];
            #pragma unroll
            for (int r = 0; r < 4; r++)
                pt[(size_t)(cjb + r) * Cout + ci] = av[r];
        }
    }
}

// ================= Frobenius norm of summed split-K partials (deterministic) =================
__global__ void fro1_kernel(const float* __restrict__ part, int nElem, int splitk,
                            float* __restrict__ blockSS) {
    int tid = threadIdx.x;
    float ss = 0.f;
    for (int idx = blockIdx.x * 256 + tid; idx < nElem; idx += 1024 * 256) {
        float s = 0.f;
        for (int z = 0; z < splitk; z++) s += part[(size_t)z * nElem + idx];
        ss += s * s;
    }
    __shared__ float red[256];
    red[tid] = ss; __syncthreads();
    for (int m = 128; m >= 1; m >>= 1) { if (tid < m) red[tid] += red[tid + m]; __syncthreads(); }
    if (tid == 0) blockSS[blockIdx.x] = red[0];
}
__global__ void fro2_kernel(const float* __restrict__ blockSS, float* __restrict__ outp) {
    int tid = threadIdx.x;
    float s = 0.f;
    for (int i = tid; i < 1024; i += 256) s += blockSS[i];
    __shared__ float red[256];
    red[tid] = s; __syncthreads();
    for (int m = 128; m >= 1; m >>= 1) { if (tid < m) red[tid] += red[tid + m]; __syncthreads(); }
    if (tid == 0) *outp = sqrtf(red[0]);
}

// ================= max-pool over points: one wave per (b,co) row, coalesced =================
__global__ void pool_kernel(const short* __restrict__ H, const short* __restrict__ L,
                            float* __restrict__ out) {
    int wave = threadIdx.x >> 6, lane = threadIdx.x & 63;
    int r = blockIdx.x * 4 + wave;             // [0, 16384): r = co*16 + b
    int co = r >> 4, b = r & 15;
    const unsigned short* h = (const unsigned short*)H + (size_t)co * LDT + b * NN;
    const unsigned short* l = (const unsigned short*)L + (size_t)co * LDT + b * NN;
    float m = -1e30f;
    #pragma unroll
    for (int it = 0; it < 2; it++) {
        int n8 = (it * 64 + lane) * 8;
        uint4 vh = *(const uint4*)&h[n8];
        uint4 vl = *(const uint4*)&l[n8];
        const unsigned* hp = (const unsigned*)&vh;
        const unsigned* lp = (const unsigned*)&vl;
        #pragma unroll
        for (int e = 0; e < 4; e++) {
            m = fmaxf(m, b2f1(hp[e]) + b2f1(lp[e]));
            m = fmaxf(m, b2f1(hp[e] >> 16) + b2f1(lp[e] >> 16));
        }
    }
    m = wave_max(m);
    if (lane == 0) out[b * 1024 + co] = m;
}

// ================= small FC: one wave per (b,o) output, lanes stride K (coalesced) =================
__global__ void fc_kernel(const float* __restrict__ in, const float* __restrict__ WtT,
                          const float* __restrict__ bias, float* __restrict__ out,
                          int K, int O, int doRelu) {
    int wave = threadIdx.x >> 6, lane = threadIdx.x & 63;
    int idx = blockIdx.x * 4 + wave;           // [0, 16*O)
    if (idx >= 16 * O) return;
    int b = idx / O, o = idx - b * O;
    const float* ib = in + (size_t)b * K;
    const float* wr = WtT + (size_t)o * K;
    float s = 0.f;
    for (int k = lane * 4; k < K; k += 256) {
        f4 a = *(const f4*)&ib[k];
        f4 wv = *(const f4*)&wr[k];
        s += a.x * wv.x + a.y * wv.y + a.z * wv.z + a.w * wv.w;
    }
    s = wave_sum(s);
    if (lane == 0) {
        s += bias[o];
        if (doRelu) s = fmaxf(s, 0.f);
        out[(size_t)b * O + o] = s;
    }
}

extern "C" void kernel_launch(void* const* d_in, const int* in_sizes, int n_in,
                              void* d_out, int out_size, void* d_ws, size_t ws_size,
                              hipStream_t stream) {
    const float* x   = (const float*)d_in[0];
    const float* w1  = (const float*)d_in[4];
    const float* b1  = (const float*)d_in[5];
    const float* w2  = (const float*)d_in[6];
    const float* b2  = (const float*)d_in[7];
    const float* w3  = (const float*)d_in[8];
    const float* b3  = (const float*)d_in[9];
    const float* fw1 = (const float*)d_in[10];
    const float* fb1 = (const float*)d_in[11];
    const float* fw2 = (const float*)d_in[12];
    const float* fb2 = (const float*)d_in[13];
    const float* fw3 = (const float*)d_in[14];
    const float* fb3 = (const float*)d_in[15];
    float* out = (float*)d_out;

    char* ws = (char*)d_ws;
    size_t off = 0;
    auto alloc = [&](size_t bytes) -> void* {
        void* p = ws + off; off += (bytes + 255) & ~(size_t)255; return p;
    };
    short* Wbuf = (short*)alloc((size_t)BB * NN * NN * 2);   // 32 MiB; Mpart aliases after V-step
    short* Zbuf = (short*)alloc((size_t)1024 * LDT * 2);     // 32 MiB raw Z slices; V output later
    short* ZSc  = (short*)alloc((size_t)1024 * LDT * 2);     // 32 MiB scaled Z slices / scaled Out (V)
    short* Z0Sc = (short*)alloc((size_t)512 * LDT * 2);      // 16 MiB scaled Z0 (first wgemm B)
    short* XRh  = (short*)alloc((size_t)512 * LDT * 2);      // 16 MiB row-major X (hi)
    short* XRl  = (short*)alloc((size_t)512 * LDT * 2);      // 16 MiB row-major X (lo)
    short* o1H  = (short*)alloc((size_t)128 * LDT * 2);
    short* o1L  = (short*)alloc((size_t)128 * LDT * 2);
    short* o2H  = (short*)alloc((size_t)512 * LDT * 2);
    short* o2L  = (short*)alloc((size_t)512 * LDT * 2);
    short* o3H  = (short*)alloc((size_t)1024 * LDT * 2);
    short* o3L  = (short*)alloc((size_t)1024 * LDT * 2);
    short* xTh  = (short*)alloc((size_t)8 * LDT * 2);
    short* xTl  = (short*)alloc((size_t)8 * LDT * 2);
    short* WtT  = (short*)alloc((size_t)1024 * 1536 * 2);
    float* fwT1 = (float*)alloc((size_t)512 * 1024 * 4);
    float* fwT2 = (float*)alloc((size_t)128 * 512 * 4);
    float* fwT3 = (float*)alloc((size_t)10 * 128 * 4);
    float* sqpart = (float*)alloc((size_t)8 * LDT * 4);
    float* Wpart  = (float*)alloc((size_t)8 * BB * NN * 4);
    float* diagW  = (float*)alloc(BB * NN * 4);
    float* sq    = (float*)alloc(BB * NN * 4);
    float* dinv  = (float*)alloc(BB * NN * 4);
    float* dinvP = (float*)alloc(BB * NN * 4);
    float* cA1   = (float*)alloc(BB * NN * 4);
    float* cA2   = (float*)alloc(BB * NN * 4);
    float* cAV   = (float*)alloc(BB * NN * 4);
    float* pooled= (float*)alloc(BB * 1024 * 4);
    float* h1    = (float*)alloc(BB * 512 * 4);
    float* h2    = (float*)alloc(BB * 128 * 4);
    float* blockSS = (float*)alloc(1024 * 4);
    float* Mpart = (float*)Wbuf;      // alias: W dead after V-step
    (void)ws_size; (void)in_sizes; (void)n_in; (void)out_size;

    struct Layer {
        const short *XTh, *XTl;       // input features (transposed hi/lo)
        int C, K, Cpad, shift, Kp64, KpValid, Cout, splitk, rIdx;
        const float *Wk, *bk;
        short *OutH, *OutL;
    };
    Layer L[3] = {
        { xTh, xTl, 8,   6, 8,   3, 64,   48,   128,  64, 160, w1, b1, o1H, o1L },
        { o1H, o1L, 128, 5, 128, 7, 640,  640,  512,  32, 161, w2, b2, o2H, o2L },
        { o2H, o2L, 512, 3, 512, 9, 1536, 1536, 1024, 8,  162, w3, b3, o3H, o3L },
    };

    xt_prep_kernel<<<LDT / 256, 256, 0, stream>>>(x, xTh, xTl);
    wtrans_kernel<<<(1024 * 512 + 255) / 256, 256, 0, stream>>>(fw1, fwT1, 1024, 512);
    wtrans_kernel<<<(512 * 128 + 255) / 256, 256, 0, stream>>>(fw2, fwT2, 512, 128);
    wtrans_kernel<<<(128 * 10 + 255) / 256, 256, 0, stream>>>(fw3, fwT3, 128, 10);

    for (int l = 0; l < 3; l++) {
        const Layer& P = L[l];
        int NC = (P.C + 127) / 128;
        int CR = (P.Cpad < 64) ? 64 : P.Cpad;    // row-major stride (zero-padded)
        wtt_prep_kernel<<<(P.Cout * P.Kp64 + 255) / 256, 256, 0, stream>>>(
            P.Wk, WtT, P.Kp64, P.KpValid, P.Cpad - 1, P.shift, (l == 0) ? 6 : P.C, P.Cout);
        sqt_part_kernel<<<dim3(LDT / 256, NC), 256, 0, stream>>>(P.XTh, P.XTl, P.C, sqpart);
        sqt_red_kernel<<<LDT / 256, 256, 0, stream>>>(sqpart, NC, sq);
        // once-per-layer transpose to row-major [point][CR]
        xpose_kernel<<<dim3(LDT / 128, CR / 64), 256, 0, stream>>>(
            P.XTh, P.XTl, P.Cpad, CR, XRh, XRl);
        adj_mfma_kernel<<<dim3(8, 8, BB), 256, 0, stream>>>(XRh, XRl, CR / 64, CR, sq,
                                                            Wbuf, Wpart, diagW);
        reduce_prep_kernel<<<BB * NN / 256, 256, 0, stream>>>(Wpart, diagW, dinv, dinvP, cA1, cA2, cAV);

        // scaled Z0 for the first wgemm's B operand
        scale_sc_kernel<<<(P.Cpad * LDT / 8 + 255) / 256, 256, 0, stream>>>(
            P.XTh, dinv, Z0Sc, P.Cpad * LDT / 8);

        int cT = (P.Cpad + 127) / 128;
        bool sm = (P.Cpad <= 128);               // small-C: 64-row i-tiles, 2x grid
        auto sliceR = [&](int k) -> short* { return Zbuf + (size_t)(k - 1) * P.Cpad * LDT; };
        auto sliceS = [&](int k) -> short* { return ZSc  + (size_t)(k - 1) * P.Cpad * LDT; };
        // Z1 = -dinv .* (W @ Z0sc)
        if (P.K > 2) {
            if (sm) wgemm2_kernel<false, false, true, 64><<<dim3(NN / 64, cT, BB), 512, 0, stream>>>(
                        Wbuf, Z0Sc, cA1, 0.f, (const short*)nullptr, dinv, sliceR(1), sliceS(1), P.Cpad);
            else    wgemm2_kernel<false, false, true, 128><<<dim3(NN / 128, cT, BB), 512, 0, stream>>>(
                        Wbuf, Z0Sc, cA1, 0.f, (const short*)nullptr, dinv, sliceR(1), sliceS(1), P.Cpad);
        } else {
            if (sm) wgemm2_kernel<false, false, false, 64><<<dim3(NN / 64, cT, BB), 512, 0, stream>>>(
                        Wbuf, Z0Sc, cA1, 0.f, (const short*)nullptr, dinv, sliceR(1), (short*)nullptr, P.Cpad);
            else    wgemm2_kernel<false, false, false, 128><<<dim3(NN / 128, cT, BB), 512, 0, stream>>>(
                        Wbuf, Z0Sc, cA1, 0.f, (const short*)nullptr, dinv, sliceR(1), (short*)nullptr, P.Cpad);
        }
        // Zk = -2*dinv .* (W @ Zsc_{k-1}) - Z_{k-2}
        for (int k = 2; k < P.K; k++) {
            const short* prevT = (k == 2) ? P.XTh : sliceR(k - 2);
            if (k < P.K - 1) {
                if (sm) wgemm2_kernel<true, false, true, 64><<<dim3(NN / 64, cT, BB), 512, 0, stream>>>(
                            Wbuf, sliceS(k - 1), cA2, -1.f, prevT, dinv, sliceR(k), sliceS(k), P.Cpad);
                else    wgemm2_kernel<true, false, true, 128><<<dim3(NN / 128, cT, BB), 512, 0, stream>>>(
                            Wbuf, sliceS(k - 1), cA2, -1.f, prevT, dinv, sliceR(k), sliceS(k), P.Cpad);
            } else {
                if (sm) wgemm2_kernel<true, false, false, 64><<<dim3(NN / 64, cT, BB), 512, 0, stream>>>(
                            Wbuf, sliceS(k - 1), cA2, -1.f, prevT, dinv, sliceR(k), (short*)nullptr, P.Cpad);
                else    wgemm2_kernel<true, false, false, 128><<<dim3(NN / 128, cT, BB), 512, 0, stream>>>(
                            Wbuf, sliceS(k - 1), cA2, -1.f, prevT, dinv, sliceR(k), (short*)nullptr, P.Cpad);
            }
        }
        // out = relu(Zcat @ Wk + b); also emits ZSc = dinvP .* out (V-step input)
        fgemm_mfma_kernel<<<dim3(LDT / 128, P.Cout / 128), 512, 0, stream>>>(
            P.XTh, Zbuf, WtT, P.Kp64, P.KpValid, P.Cpad, P.bk, dinvP, P.OutH, P.OutL, ZSc);
        // V = out - dinvP .* (W_nodiag @ ZSc); V -> Zbuf
        int cTV = P.Cout / 128;
        if (P.Cout <= 128)
            wgemm2_kernel<true, true, false, 64><<<dim3(NN / 64, cTV, BB), 512, 0, stream>>>(
                Wbuf, ZSc, cAV, 1.f, P.OutH, dinvP, Zbuf, (short*)nullptr, P.Cout);
        else
            wgemm2_kernel<true, true, false, 128><<<dim3(NN / 128, cTV, BB), 512, 0, stream>>>(
                Wbuf, ZSc, cAV, 1.f, P.OutH, dinvP, Zbuf, (short*)nullptr, P.Cout);
        int kChunk = LDT / P.splitk;
        mgemm_mfma_kernel<<<dim3(P.Cout / 128, P.Cout / 128, P.splitk), 256, 0, stream>>>(
            P.OutH, Zbuf, Mpart, P.Cout, kChunk);
        fro1_kernel<<<1024, 256, 0, stream>>>(Mpart, P.Cout * P.Cout, P.splitk, blockSS);
        fro2_kernel<<<1, 256, 0, stream>>>(blockSS, out + P.rIdx);
    }
    pool_kernel<<<16384 / 4, 256, 0, stream>>>(o3H, o3L, pooled);
    fc_kernel<<<(16 * 512 + 3) / 4, 256, 0, stream>>>(pooled, fwT1, fb1, h1, 1024, 512, 1);
    fc_kernel<<<(16 * 128 + 3) / 4, 256, 0, stream>>>(h1, fwT2, fb2, h2, 512, 128, 1);
    fc_kernel<<<(16 * 10 + 3) / 4, 256, 0, stream>>>(h2, fwT3, fb3, out, 128, 10, 0);
}

// Round 14
// 920.327 us; speedup vs baseline: 1.0540x; 1.0540x over previous
//
#include <hip/hip_runtime.h>

#define BB 16
#define NN 1024
#define LDT 16384          // column count of all transposed feature buffers

typedef float4 f4;
typedef __attribute__((ext_vector_type(8))) short bf16x8;
typedef __attribute__((ext_vector_type(4))) float f32x4;

// bf16 pack/unpack (RNE)
__device__ __forceinline__ unsigned f2b1(float f) {
    unsigned u = __builtin_bit_cast(unsigned, f);
    return (u + 0x7fffu + ((u >> 16) & 1u)) >> 16;
}
__device__ __forceinline__ float b2f1(unsigned s) {
    unsigned u = (s & 0xffffu) << 16;
    return __builtin_bit_cast(float, u);
}

// LDS tile element offset, swizzled. Tile is [row][k] = [R][64] shorts.
// g = (row&7) ^ ((row>>3)&7): conflict-free for transpose-writes, row-copies and
// fragment reads, with compile-time register indexing everywhere.
#define SW(r, k) ((r) * 64 + ((k) ^ (((((r) & 7) ^ (((r) >> 3) & 7))) << 3)))

// ---- async global->LDS, 16B per lane. LDS dest = wave-uniform base + lane*16
// (linear); the global source chunk is pre-swizzled so data lands at SW(r,k):
// segment s covers rows 8s..8s+7; lane l -> row 8s+(l>>3), holds chunk
// jc = (l&7) ^ (l>>3) ^ (s&7) (== SW's placement). Reads stay unchanged.
__device__ __forceinline__ void gload16(const unsigned short* g, short* l) {
    __builtin_amdgcn_global_load_lds(
        (const __attribute__((address_space(1))) unsigned int*)g,
        (__attribute__((address_space(3))) unsigned int*)l, 16, 0, 0);
}

__device__ __forceinline__ float wave_sum(float v) {
    #pragma unroll
    for (int m = 32; m >= 1; m >>= 1) v += __shfl_xor(v, m);
    return v;
}
__device__ __forceinline__ float wave_max(float v) {
    #pragma unroll
    for (int m = 32; m >= 1; m >>= 1) v = fmaxf(v, __shfl_xor(v, m));
    return v;
}

// ---- transpose staging (pair-pack): T[r=0..127][c=0..63] = src[(c0+c)*LDT + col_base + r] ----
__device__ __forceinline__ void stage_tr(short* T, const unsigned short* src,
                                         size_t col_base, int c0, int Cvalid, int tid) {
    #pragma unroll
    for (int n = 0; n < 2; n++) {
        int q = n * 256 + tid;
        int p = q >> 4, h = q & 15;
        int cg = c0 + 2 * p;
        uint4 r0 = make_uint4(0, 0, 0, 0), r1 = make_uint4(0, 0, 0, 0);
        if (cg < Cvalid)     r0 = *(const uint4*)&src[(size_t)cg * LDT + col_base + 8 * h];
        if (cg + 1 < Cvalid) r1 = *(const uint4*)&src[(size_t)(cg + 1) * LDT + col_base + 8 * h];
        const unsigned* a0 = (const unsigned*)&r0;
        const unsigned* a1 = (const unsigned*)&r1;
        #pragma unroll
        for (int e = 0; e < 8; e++) {
            unsigned lo = (e & 1) ? (a0[e >> 1] >> 16) : (a0[e >> 1] & 0xffffu);
            unsigned hi = (e & 1) ? (a1[e >> 1] >> 16) : (a1[e >> 1] & 0xffffu);
            int r = 8 * h + e;
            *(unsigned*)&T[SW(r, 2 * p)] = lo | (hi << 16);
        }
    }
}

// ================= input prep =================
__global__ void xt_prep_kernel(const float* __restrict__ x, short* __restrict__ xh,
                               short* __restrict__ xl) {
    int m = blockIdx.x * 256 + threadIdx.x;
    #pragma unroll
    for (int c = 0; c < 8; c++) {
        float v = (c < 6) ? x[(size_t)m * 6 + c] : 0.f;
        unsigned h = f2b1(v);
        unsigned l = f2b1(v - b2f1(h));
        xh[(size_t)c * LDT + m] = (short)h;
        xl[(size_t)c * LDT + m] = (short)l;
    }
}

__global__ void wtt_prep_kernel(const float* __restrict__ Wk, short* __restrict__ WtT,
                                int Kp64, int KpValid, int CpadM1, int shift, int Cin, int Cout) {
    int idx = blockIdx.x * 256 + threadIdx.x;
    if (idx >= Cout * Kp64) return;
    int co = idx / Kp64, kk = idx - co * Kp64;
    int c = kk & CpadM1;
    float val = 0.f;
    if (kk < KpValid && c < Cin)
        val = Wk[((size_t)(kk >> shift) * Cin + c) * Cout + co];
    WtT[(size_t)co * Kp64 + kk] = (short)f2b1(val);
}

// ---- FC weight transpose: WtT[o][k] = Wt[k][o] ----
__global__ void wtrans_kernel(const float* __restrict__ Wt, float* __restrict__ WtT,
                              int K, int O) {
    int idx = blockIdx.x * 256 + threadIdx.x;
    if (idx >= K * O) return;
    int o = idx / K, k = idx - o * K;
    WtT[idx] = Wt[(size_t)k * O + o];
}

// ---- scaled copy: dst[c][m] = bf16( src[c][m] * coeff[m] ) ----
__global__ void scale_sc_kernel(const short* __restrict__ src, const float* __restrict__ coeff,
                                short* __restrict__ dst, int total8) {
    int q = blockIdx.x * 256 + threadIdx.x;
    if (q >= total8) return;
    size_t base = (size_t)q * 8;
    int m8 = (int)(base & (LDT - 1));
    uint4 v = *(const uint4*)&((const unsigned short*)src)[base];
    f4 c0 = *(const f4*)&coeff[m8];
    f4 c1 = *(const f4*)&coeff[m8 + 4];
    const float* cp0 = (const float*)&c0;
    const float* cp1 = (const float*)&c1;
    unsigned* vp = (unsigned*)&v;
    #pragma unroll
    for (int e = 0; e < 4; e++) {
        float se0 = (e < 2) ? cp0[2 * e] : cp1[2 * e - 4];
        float se1 = (e < 2) ? cp0[2 * e + 1] : cp1[2 * e - 3];
        vp[e] = f2b1(b2f1(vp[e]) * se0) | (f2b1(b2f1(vp[e] >> 16) * se1) << 16);
    }
    *(uint4*)&((unsigned short*)dst)[base] = v;
}

// ---- layer-wide transpose: XR[m][c] = XT[c][m], rows padded/zeroed to CR ----
__global__ __launch_bounds__(256)
void xpose_kernel(const short* __restrict__ H, const short* __restrict__ L,
                  int Cvalid, int CR, short* __restrict__ XRh, short* __restrict__ XRl) {
    __shared__ short Th[128 * 64], Tl[128 * 64];
    int tid = threadIdx.x;
    int m0 = blockIdx.x * 128, c0 = blockIdx.y * 64;
    stage_tr(Th, (const unsigned short*)H, m0, c0, Cvalid, tid);
    stage_tr(Tl, (const unsigned short*)L, m0, c0, Cvalid, tid);
    __syncthreads();
    #pragma unroll
    for (int n = 0; n < 4; n++) {
        int q = n * 256 + tid;
        int r = q >> 3, j = q & 7;
        int g = (r & 7) ^ ((r >> 3) & 7);
        *(uint4*)&XRh[(size_t)(m0 + r) * CR + c0 + 8 * j] = *(const uint4*)&Th[r * 64 + 8 * (j ^ g)];
        *(uint4*)&XRl[(size_t)(m0 + r) * CR + c0 + 8 * j] = *(const uint4*)&Tl[r * 64 + 8 * (j ^ g)];
    }
}

// ================= squared norms from hi/lo (partial over 128-c chunks) =================
__global__ void sqt_part_kernel(const short* __restrict__ H, const short* __restrict__ L,
                                int C, float* __restrict__ dst) {
    int m = blockIdx.x * 256 + threadIdx.x;
    int cb = blockIdx.y * 128;
    int ce = min(cb + 128, C);
    const unsigned short* Hp = (const unsigned short*)H;
    const unsigned short* Lp = (const unsigned short*)L;
    float s = 0.f;
    for (int c = cb; c < ce; c++) {
        float v = b2f1(Hp[(size_t)c * LDT + m]) + b2f1(Lp[(size_t)c * LDT + m]);
        s += v * v;
    }
    dst[(size_t)blockIdx.y * LDT + m] = s;
}
__global__ void sqt_red_kernel(const float* __restrict__ part, int NC, float* __restrict__ sq) {
    int m = blockIdx.x * 256 + threadIdx.x;
    float s = 0.f;
    for (int y = 0; y < NC; y++) s += part[(size_t)y * LDT + m];
    sq[m] = s;
}

// ====== adjacency + fused row-sum partials: W[b][j][i] = exp(2G - sq_i - sq_j) ======
// 4 waves; wave tile 64(j) x 64(i). Staging via global_load_lds from row-major XR.
// Off-diag partial sums -> Wpart; diag -> diagW.
__global__ __launch_bounds__(256)
void adj_mfma_kernel(const short* __restrict__ XRh, const short* __restrict__ XRl,
                     int ck64, int CR, const float* __restrict__ sq,
                     short* __restrict__ Wb, float* __restrict__ Wpart,
                     float* __restrict__ diagW) {
    __shared__ short Ah[128 * 64], Al[128 * 64], Bh[128 * 64], Bl[128 * 64];
    __shared__ float jpart[128][2];
    int tid = threadIdx.x, lane = tid & 63, w = tid >> 6;
    int wj = w >> 1, wi = w & 1;
    int b = blockIdx.z, i0 = blockIdx.x * 128, j0 = blockIdx.y * 128;
    size_t bo = (size_t)b * NN;
    f32x4 acc[4][4] = {};
    const unsigned short* Hp = (const unsigned short*)XRh;
    const unsigned short* Lp = (const unsigned short*)XRl;
    // per-lane pre-swizzled source offsets for the 4 segments this wave stages per tile
    int rr = lane >> 3, jj = lane & 7;
    size_t offI[4], offJ[4];
    #pragma unroll
    for (int m = 0; m < 4; m++) {
        int s = w + m * 4;
        int jc = jj ^ rr ^ (s & 7);
        offI[m] = (size_t)(bo + i0 + 8 * s + rr) * CR + 8 * jc;
        offJ[m] = (size_t)(bo + j0 + 8 * s + rr) * CR + 8 * jc;
    }
    for (int t = 0; t < ck64; t++) {
        int c0 = t * 64;
        #pragma unroll
        for (int m = 0; m < 4; m++) {
            int s512 = (w + m * 4) * 512;
            gload16(Hp + offI[m] + c0, Ah + s512);
            gload16(Lp + offI[m] + c0, Al + s512);
            gload16(Hp + offJ[m] + c0, Bh + s512);
            gload16(Lp + offJ[m] + c0, Bl + s512);
        }
        __syncthreads();
        int la = lane & 15;
        #pragma unroll
        for (int ks = 0; ks < 2; ks++) {
            int kb = ks * 32 + (lane >> 4) * 8;
            bf16x8 jh[4], jl[4], ih[4], il[4];
            #pragma unroll
            for (int f = 0; f < 4; f++) {
                int jr = wj * 64 + f * 16 + la;
                jh[f] = *(const bf16x8*)&Bh[SW(jr, kb)];
                jl[f] = *(const bf16x8*)&Bl[SW(jr, kb)];
                int ir = wi * 64 + f * 16 + la;
                ih[f] = *(const bf16x8*)&Ah[SW(ir, kb)];
                il[f] = *(const bf16x8*)&Al[SW(ir, kb)];
            }
            #pragma unroll
            for (int fq = 0; fq < 4; fq++)
                #pragma unroll
                for (int fi = 0; fi < 4; fi++) {
                    acc[fq][fi] = __builtin_amdgcn_mfma_f32_16x16x32_bf16(jh[fq], ih[fi], acc[fq][fi], 0, 0, 0);
                    acc[fq][fi] = __builtin_amdgcn_mfma_f32_16x16x32_bf16(jh[fq], il[fi], acc[fq][fi], 0, 0, 0);
                    acc[fq][fi] = __builtin_amdgcn_mfma_f32_16x16x32_bf16(jl[fq], ih[fi], acc[fq][fi], 0, 0, 0);
                }
        }
        __syncthreads();
    }
    const float* sqb = sq + bo;
    unsigned short* Wout = (unsigned short*)Wb + bo * NN;
    float si_[4];
    int iloc[4];
    #pragma unroll
    for (int fi = 0; fi < 4; fi++) {
        iloc[fi] = i0 + wi * 64 + fi * 16 + (lane & 15);
        si_[fi] = sqb[iloc[fi]];
    }
    #pragma unroll
    for (int fq = 0; fq < 4; fq++) {
        int jb = j0 + wj * 64 + fq * 16 + (lane >> 4) * 4;
        #pragma unroll
        for (int r = 0; r < 4; r++) {
            int j = jb + r;
            float sj = sqb[j];
            float p = 0.f;
            #pragma unroll
            for (int fi = 0; fi < 4; fi++) {
                float val = __expf(2.f * ((const float*)&acc[fq][fi])[r] - si_[fi] - sj);
                Wout[(size_t)j * NN + iloc[fi]] = (unsigned short)f2b1(val);
                if (iloc[fi] == j) diagW[bo + j] = val;
                else p += val;
            }
            p += __shfl_xor(p, 1); p += __shfl_xor(p, 2);
            p += __shfl_xor(p, 4); p += __shfl_xor(p, 8);
            if ((lane & 15) == 0)
                jpart[wj * 64 + fq * 16 + (lane >> 4) * 4 + r][wi] = p;
        }
    }
    __syncthreads();
    if (tid < 128)
        Wpart[(size_t)blockIdx.x * (BB * NN) + bo + j0 + tid] = jpart[tid][0] + jpart[tid][1];
}

// ====== reduce partials -> coefficient vectors ======
__global__ void reduce_prep_kernel(const float* __restrict__ Wpart, const float* __restrict__ diagW,
                                   float* dinv, float* dinvP, float* cA1, float* cA2, float* cAV) {
    int idx = blockIdx.x * 256 + threadIdx.x;    // [0, 16384)
    float s = 0.f;
    #pragma unroll
    for (int x = 0; x < 8; x++) s += Wpart[(size_t)x * (BB * NN) + idx];
    float d = diagW[idx];
    float dv = rsqrtf(s + d);    // full sum (incl diag)
    float dp = rsqrtf(s);        // exact off-diag sum (no cancellation)
    dinv[idx] = dv; dinvP[idx] = dp;
    cA1[idx] = -dv; cA2[idx] = -2.f * dv; cAV[idx] = -dp;
}

// ====== W-GEMM (8 waves): Dst[c][i] = cA_i * sum_j W[i][j]*Bsc[c][j] (+ prevSign*Prev[c][i]) ======
// Staging via global_load_lds (linear LDS dest, pre-swizzled global chunk).
// XB = i-tile rows (128 or 64). XB=64 doubles the grid for small-C launches
// (occupancy fix for layer-1/2 Chebyshev chains). Per-element math identical.
template<bool HAS_PREV, bool SKIP_DIAG, bool WRITE_SC, int XB>
__global__ __launch_bounds__(512)
void wgemm2_kernel(const short* __restrict__ W, const short* __restrict__ Bsc,
                   const float* __restrict__ cAvec, float prevSign,
                   const short* __restrict__ PrevT, const float* __restrict__ scVec,
                   short* __restrict__ DstT, short* __restrict__ DstSc, int Cvalid) {
    __shared__ short As[XB * 64], Bs[128 * 64];
    constexpr int NFI = XB / 64;                 // i-frags per wave (2 or 1)
    int tid = threadIdx.x, lane = tid & 63, w = tid >> 6;
    int wcc = w >> 2, wii = w & 3;               // wave tile: 64 c x XB/4 i
    int b = blockIdx.z, i0 = blockIdx.x * XB, c0 = blockIdx.y * 128;
    size_t bo = (size_t)b * NN;
    const unsigned short* Wp = (const unsigned short*)W + bo * NN;
    const unsigned short* Bp = (const unsigned short*)Bsc;
    int rr = lane >> 3, jj = lane & 7;
    int jc = jj ^ rr ^ (w & 7);                  // (w+8)&7 == w&7
    const unsigned short* aR0 = Wp + (size_t)(i0 + 8 * w + rr) * NN + 8 * jc;
    const unsigned short* aR1 = Wp + (size_t)(i0 + 8 * ((XB == 128) ? w + 8 : w) + rr) * NN + 8 * jc;
    const unsigned short* bR0 = Bp + (size_t)(c0 + 8 * w + rr) * LDT + bo + 8 * jc;
    const unsigned short* bR1 = Bp + (size_t)(c0 + 8 * (w + 8) + rr) * LDT + bo + 8 * jc;
    short* aL0 = As + w * 512;
    short* aL1 = As + ((XB == 128) ? w + 8 : w) * 512;
    short* bL0 = Bs + w * 512; short* bL1 = Bs + (w + 8) * 512;
    f32x4 acc[4][NFI] = {};
    for (int k0 = 0; k0 < NN; k0 += 64) {
        gload16(aR0 + k0, aL0);
        if (XB == 128) gload16(aR1 + k0, aL1);
        gload16(bR0 + k0, bL0);
        gload16(bR1 + k0, bL1);
        __syncthreads();                          // compiler drains vmcnt before barrier
        if (SKIP_DIAG) {
            if (k0 >= i0 && k0 < i0 + XB) {       // diag band intersects this k-tile
                if (tid < 64) As[SW((k0 - i0) + tid, tid)] = 0;
                __syncthreads();
            }
        }
        int la = lane & 15;
        #pragma unroll
        for (int ks = 0; ks < 2; ks++) {
            int kb = ks * 32 + (lane >> 4) * 8;
            bf16x8 ac[4], bi[NFI];
            #pragma unroll
            for (int f = 0; f < 4; f++) ac[f] = *(const bf16x8*)&Bs[SW(wcc * 64 + f * 16 + la, kb)];
            #pragma unroll
            for (int f = 0; f < NFI; f++) bi[f] = *(const bf16x8*)&As[SW(wii * (XB / 4) + f * 16 + la, kb)];
            #pragma unroll
            for (int fq = 0; fq < 4; fq++)
                #pragma unroll
                for (int fi = 0; fi < NFI; fi++)
                    acc[fq][fi] = __builtin_amdgcn_mfma_f32_16x16x32_bf16(ac[fq], bi[fi], acc[fq][fi], 0, 0, 0);
        }
        __syncthreads();
    }
    const unsigned short* Pp = (const unsigned short*)PrevT;
    unsigned short* Dp = (unsigned short*)DstT;
    unsigned short* Sp = (unsigned short*)DstSc;
    #pragma unroll
    for (int fi = 0; fi < NFI; fi++) {
        int i = i0 + wii * (XB / 4) + fi * 16 + (lane & 15);
        float ca = cAvec[bo + i];
        float sc = WRITE_SC ? scVec[bo + i] : 0.f;
        #pragma unroll
        for (int fq = 0; fq < 4; fq++) {
            int cb = c0 + wcc * 64 + fq * 16 + (lane >> 4) * 4;
            const float* av = (const float*)&acc[fq][fi];
            #pragma unroll
            for (int r = 0; r < 4; r++) {
                int c = cb + r;
                if (c < Cvalid) {
                    float v = ca * av[r];
                    if (HAS_PREV) v += prevSign * b2f1(Pp[(size_t)c * LDT + bo + i]);
                    Dp[(size_t)c * LDT + bo + i] = (unsigned short)f2b1(v);
                    if (WRITE_SC) Sp[(size_t)c * LDT + bo + i] = (unsigned short)f2b1(v * sc);
                }
            }
        }
    }
}

// ====== feature GEMM (8 waves): Out[co][m] = relu(sum_kk Zcat[m][kk]*Wt[kk][co] + bias) ======
// B staged via global_load_lds; A-transpose loads software-pipelined (issue t+1
// loads before tile-t MFMAs so HBM/L3 latency hides under compute).
__global__ __launch_bounds__(512)
void fgemm_mfma_kernel(const short* __restrict__ A0T, const short* __restrict__ ZrT,
                       const short* __restrict__ WtT, int Kp64, int KpValid, int Cpad,
                       const float* __restrict__ bias,
                       short* __restrict__ OutH, short* __restrict__ OutL) {
    __shared__ short As[128 * 64], Bs[128 * 64];
    int tid = threadIdx.x, lane = tid & 63, w = tid >> 6;
    int wco = w >> 2, wm = w & 3;                // wave tile: 64 co x 32 m
    int m0 = blockIdx.x * 128, co0 = blockIdx.y * 128;
    const unsigned short* A0 = (const unsigned short*)A0T;
    const unsigned short* Zr = (const unsigned short*)ZrT;
    const unsigned short* Wt = (const unsigned short*)WtT;
    // B staging addresses (gload16, row stride Kp64)
    int rr = lane >> 3, jj = lane & 7;
    int jcB = jj ^ rr ^ (w & 7);
    const unsigned short* bB0 = Wt + (size_t)(co0 + 8 * w + rr) * Kp64 + 8 * jcB;
    const unsigned short* bB1 = Wt + (size_t)(co0 + 8 * (w + 8) + rr) * Kp64 + 8 * jcB;
    short* bL0 = Bs + w * 512; short* bL1 = Bs + (w + 8) * 512;
    int p = tid >> 4, h = tid & 15;
    uint4 ra0, ra1;
    auto loadA = [&](int kk0) {
        int kg0 = kk0 + 2 * p;
        ra0 = make_uint4(0, 0, 0, 0); ra1 = make_uint4(0, 0, 0, 0);
        if (kg0 < KpValid) {
            const unsigned short* s0 = (kg0 < Cpad) ? (A0 + (size_t)kg0 * LDT)
                                                    : (Zr + (size_t)(kg0 - Cpad) * LDT);
            ra0 = *(const uint4*)&s0[m0 + 8 * h];
        }
        if (kg0 + 1 < KpValid) {
            int kg1 = kg0 + 1;
            const unsigned short* s1 = (kg1 < Cpad) ? (A0 + (size_t)kg1 * LDT)
                                                    : (Zr + (size_t)(kg1 - Cpad) * LDT);
            ra1 = *(const uint4*)&s1[m0 + 8 * h];
        }
    };
    f32x4 acc[4][2] = {};
    loadA(0);
    for (int kk0 = 0; kk0 < Kp64; kk0 += 64) {
        {   // unpack held A regs (tile kk0) -> LDS, compile-time e indexing
            const unsigned* a0 = (const unsigned*)&ra0;
            const unsigned* a1 = (const unsigned*)&ra1;
            #pragma unroll
            for (int e = 0; e < 8; e++) {
                unsigned lo = (e & 1) ? (a0[e >> 1] >> 16) : (a0[e >> 1] & 0xffffu);
                unsigned hi = (e & 1) ? (a1[e >> 1] >> 16) : (a1[e >> 1] & 0xffffu);
                *(unsigned*)&As[SW(8 * h + e, 2 * p)] = lo | (hi << 16);
            }
        }
        gload16(bB0 + kk0, bL0);                 // B: weight rows, async DMA
        gload16(bB1 + kk0, bL1);
        __syncthreads();
        if (kk0 + 64 < Kp64) loadA(kk0 + 64);    // issue next A loads under MFMAs
        int la = lane & 15;
        #pragma unroll
        for (int ks = 0; ks < 2; ks++) {
            int kb = ks * 32 + (lane >> 4) * 8;
            bf16x8 ac[4], bm[2];
            #pragma unroll
            for (int f = 0; f < 4; f++) ac[f] = *(const bf16x8*)&Bs[SW(wco * 64 + f * 16 + la, kb)];
            #pragma unroll
            for (int f = 0; f < 2; f++) bm[f] = *(const bf16x8*)&As[SW(wm * 32 + f * 16 + la, kb)];
            #pragma unroll
            for (int fq = 0; fq < 4; fq++)
                #pragma unroll
                for (int fi = 0; fi < 2; fi++)
                    acc[fq][fi] = __builtin_amdgcn_mfma_f32_16x16x32_bf16(ac[fq], bm[fi], acc[fq][fi], 0, 0, 0);
        }
        __syncthreads();
    }
    unsigned short* OH = (unsigned short*)OutH;
    unsigned short* OL = (unsigned short*)OutL;
    #pragma unroll
    for (int fi = 0; fi < 2; fi++) {
        int m = m0 + wm * 32 + fi * 16 + (lane & 15);
        #pragma unroll
        for (int fq = 0; fq < 4; fq++) {
            int cb = co0 + wco * 64 + fq * 16 + (lane >> 4) * 4;
            const float* av = (const float*)&acc[fq][fi];
            #pragma unroll
            for (int r = 0; r < 4; r++) {
                int co = cb + r;
                float v = av[r] + bias[co];
                v = v > 0.f ? v : 0.f;
                unsigned ph = f2b1(v);
                unsigned pl = f2b1(v - b2f1(ph));
                OH[(size_t)co * LDT + m] = (unsigned short)ph;
                OL[(size_t)co * LDT + m] = (unsigned short)pl;
            }
        }
    }
}

// ====== M partials: Mpart[z][cj][ci] = sum_{m in chunk} XT[ci][m]*VT[cj][m] ======
__global__ __launch_bounds__(256)
void mgemm_mfma_kernel(const short* __restrict__ XT, const short* __restrict__ VT,
                       float* __restrict__ Mpart, int Cout, int kChunk) {
    __shared__ short As[128 * 64], Bs[128 * 64];
    int tid = threadIdx.x, lane = tid & 63, w = tid >> 6;
    int wcj = w >> 1, wci = w & 1;
    int ci0 = blockIdx.x * 128, cj0 = blockIdx.y * 128;
    int kStart = blockIdx.z * kChunk;
    const unsigned short* Xp = (const unsigned short*)XT + (size_t)ci0 * LDT;
    const unsigned short* Vp = (const unsigned short*)VT + (size_t)cj0 * LDT;
    // hoisted per-lane source addresses: 4 waves x 4 segments each
    int rr = lane >> 3, jj = lane & 7;
    const unsigned short* aB[4];
    const unsigned short* bB[4];
    short* aL[4]; short* bL[4];
    #pragma unroll
    for (int n = 0; n < 4; n++) {
        int s = w + n * 4;
        int jc = jj ^ rr ^ (s & 7);
        aB[n] = Xp + (size_t)(8 * s + rr) * LDT + 8 * jc;
        bB[n] = Vp + (size_t)(8 * s + rr) * LDT + 8 * jc;
        aL[n] = As + s * 512; bL[n] = Bs + s * 512;
    }
    f32x4 acc[4][4] = {};
    for (int k0 = kStart; k0 < kStart + kChunk; k0 += 64) {
        #pragma unroll
        for (int n = 0; n < 4; n++) {
            gload16(aB[n] + k0, aL[n]);
            gload16(bB[n] + k0, bL[n]);
        }
        __syncthreads();
        int la = lane & 15;
        #pragma unroll
        for (int ks = 0; ks < 2; ks++) {
            int kb = ks * 32 + (lane >> 4) * 8;
            bf16x8 aj[4], bi[4];
            #pragma unroll
            for (int f = 0; f < 4; f++) {
                aj[f] = *(const bf16x8*)&Bs[SW(wcj * 64 + f * 16 + la, kb)];   // cj frags
                bi[f] = *(const bf16x8*)&As[SW(wci * 64 + f * 16 + la, kb)];   // ci frags
            }
            #pragma unroll
            for (int fq = 0; fq < 4; fq++)
                #pragma unroll
                for (int fi = 0; fi < 4; fi++)
                    acc[fq][fi] = __builtin_amdgcn_mfma_f32_16x16x32_bf16(aj[fq], bi[fi], acc[fq][fi], 0, 0, 0);
        }
        __syncthreads();
    }
    float* pt = Mpart + (size_t)blockIdx.z * Cout * Cout;
    #pragma unroll
    for (int fq = 0; fq < 4; fq++) {
        int cjb = cj0 + wcj * 64 + fq * 16 + (lane >> 4) * 4;
        #pragma unroll
        for (int fi = 0; fi < 4; fi++) {
            int ci = ci0 + wci * 64 + fi * 16 + (lane & 15);
            const float* av = (const float*)&acc[fq][fi];
            #pragma unroll
            for (int r = 0; r < 4; r++)
                pt[(size_t)(cjb + r) * Cout + ci] = av[r];
        }
    }
}

// ================= Frobenius norm of summed split-K partials (deterministic) =================
__global__ void fro1_kernel(const float* __restrict__ part, int nElem, int splitk,
                            float* __restrict__ blockSS) {
    int tid = threadIdx.x;
    float ss = 0.f;
    for (int idx = blockIdx.x * 256 + tid; idx < nElem; idx += 1024 * 256) {
        float s = 0.f;
        for (int z = 0; z < splitk; z++) s += part[(size_t)z * nElem + idx];
        ss += s * s;
    }
    __shared__ float red[256];
    red[tid] = ss; __syncthreads();
    for (int m = 128; m >= 1; m >>= 1) { if (tid < m) red[tid] += red[tid + m]; __syncthreads(); }
    if (tid == 0) blockSS[blockIdx.x] = red[0];
}
__global__ void fro2_kernel(const float* __restrict__ blockSS, float* __restrict__ outp) {
    int tid = threadIdx.x;
    float s = 0.f;
    for (int i = tid; i < 1024; i += 256) s += blockSS[i];
    __shared__ float red[256];
    red[tid] = s; __syncthreads();
    for (int m = 128; m >= 1; m >>= 1) { if (tid < m) red[tid] += red[tid + m]; __syncthreads(); }
    if (tid == 0) *outp = sqrtf(red[0]);
}

// ================= max-pool over points: one wave per (b,co) row, coalesced =================
__global__ void pool_kernel(const short* __restrict__ H, const short* __restrict__ L,
                            float* __restrict__ out) {
    int wave = threadIdx.x >> 6, lane = threadIdx.x & 63;
    int r = blockIdx.x * 4 + wave;             // [0, 16384): r = co*16 + b
    int co = r >> 4, b = r & 15;
    const unsigned short* h = (const unsigned short*)H + (size_t)co * LDT + b * NN;
    const unsigned short* l = (const unsigned short*)L + (size_t)co * LDT + b * NN;
    float m = -1e30f;
    #pragma unroll
    for (int it = 0; it < 2; it++) {
        int n8 = (it * 64 + lane) * 8;
        uint4 vh = *(const uint4*)&h[n8];
        uint4 vl = *(const uint4*)&l[n8];
        const unsigned* hp = (const unsigned*)&vh;
        const unsigned* lp = (const unsigned*)&vl;
        #pragma unroll
        for (int e = 0; e < 4; e++) {
            m = fmaxf(m, b2f1(hp[e]) + b2f1(lp[e]));
            m = fmaxf(m, b2f1(hp[e] >> 16) + b2f1(lp[e] >> 16));
        }
    }
    m = wave_max(m);
    if (lane == 0) out[b * 1024 + co] = m;
}

// ================= small FC: one wave per (b,o) output, lanes stride K (coalesced) =================
__global__ void fc_kernel(const float* __restrict__ in, const float* __restrict__ WtT,
                          const float* __restrict__ bias, float* __restrict__ out,
                          int K, int O, int doRelu) {
    int wave = threadIdx.x >> 6, lane = threadIdx.x & 63;
    int idx = blockIdx.x * 4 + wave;           // [0, 16*O)
    if (idx >= 16 * O) return;
    int b = idx / O, o = idx - b * O;
    const float* ib = in + (size_t)b * K;
    const float* wr = WtT + (size_t)o * K;
    float s = 0.f;
    for (int k = lane * 4; k < K; k += 256) {
        f4 a = *(const f4*)&ib[k];
        f4 wv = *(const f4*)&wr[k];
        s += a.x * wv.x + a.y * wv.y + a.z * wv.z + a.w * wv.w;
    }
    s = wave_sum(s);
    if (lane == 0) {
        s += bias[o];
        if (doRelu) s = fmaxf(s, 0.f);
        out[(size_t)b * O + o] = s;
    }
}

extern "C" void kernel_launch(void* const* d_in, const int* in_sizes, int n_in,
                              void* d_out, int out_size, void* d_ws, size_t ws_size,
                              hipStream_t stream) {
    const float* x   = (const float*)d_in[0];
    const float* w1  = (const float*)d_in[4];
    const float* b1  = (const float*)d_in[5];
    const float* w2  = (const float*)d_in[6];
    const float* b2  = (const float*)d_in[7];
    const float* w3  = (const float*)d_in[8];
    const float* b3  = (const float*)d_in[9];
    const float* fw1 = (const float*)d_in[10];
    const float* fb1 = (const float*)d_in[11];
    const float* fw2 = (const float*)d_in[12];
    const float* fb2 = (const float*)d_in[13];
    const float* fw3 = (const float*)d_in[14];
    const float* fb3 = (const float*)d_in[15];
    float* out = (float*)d_out;

    char* ws = (char*)d_ws;
    size_t off = 0;
    auto alloc = [&](size_t bytes) -> void* {
        void* p = ws + off; off += (bytes + 255) & ~(size_t)255; return p;
    };
    short* Wbuf = (short*)alloc((size_t)BB * NN * NN * 2);   // 32 MiB; Mpart aliases after V-step
    short* Zbuf = (short*)alloc((size_t)1024 * LDT * 2);     // 32 MiB raw Z slices; V output later
    short* ZSc  = (short*)alloc((size_t)1024 * LDT * 2);     // 32 MiB scaled Z slices / scaled Out (V)
    short* Z0Sc = (short*)alloc((size_t)512 * LDT * 2);      // 16 MiB scaled Z0 (first wgemm B)
    short* XRh  = (short*)alloc((size_t)512 * LDT * 2);      // 16 MiB row-major X (hi)
    short* XRl  = (short*)alloc((size_t)512 * LDT * 2);      // 16 MiB row-major X (lo)
    short* o1H  = (short*)alloc((size_t)128 * LDT * 2);
    short* o1L  = (short*)alloc((size_t)128 * LDT * 2);
    short* o2H  = (short*)alloc((size_t)512 * LDT * 2);
    short* o2L  = (short*)alloc((size_t)512 * LDT * 2);
    short* o3H  = (short*)alloc((size_t)1024 * LDT * 2);
    short* o3L  = (short*)alloc((size_t)1024 * LDT * 2);
    short* xTh  = (short*)alloc((size_t)8 * LDT * 2);
    short* xTl  = (short*)alloc((size_t)8 * LDT * 2);
    short* WtT  = (short*)alloc((size_t)1024 * 1536 * 2);
    float* fwT1 = (float*)alloc((size_t)512 * 1024 * 4);
    float* fwT2 = (float*)alloc((size_t)128 * 512 * 4);
    float* fwT3 = (float*)alloc((size_t)10 * 128 * 4);
    float* sqpart = (float*)alloc((size_t)8 * LDT * 4);
    float* Wpart  = (float*)alloc((size_t)8 * BB * NN * 4);
    float* diagW  = (float*)alloc(BB * NN * 4);
    float* sq    = (float*)alloc(BB * NN * 4);
    float* dinv  = (float*)alloc(BB * NN * 4);
    float* dinvP = (float*)alloc(BB * NN * 4);
    float* cA1   = (float*)alloc(BB * NN * 4);
    float* cA2   = (float*)alloc(BB * NN * 4);
    float* cAV   = (float*)alloc(BB * NN * 4);
    float* pooled= (float*)alloc(BB * 1024 * 4);
    float* h1    = (float*)alloc(BB * 512 * 4);
    float* h2    = (float*)alloc(BB * 128 * 4);
    float* blockSS = (float*)alloc(1024 * 4);
    float* Mpart = (float*)Wbuf;      // alias: W dead after V-step
    (void)ws_size; (void)in_sizes; (void)n_in; (void)out_size;

    struct Layer {
        const short *XTh, *XTl;       // input features (transposed hi/lo)
        int C, K, Cpad, shift, Kp64, KpValid, Cout, splitk, rIdx;
        const float *Wk, *bk;
        short *OutH, *OutL;
    };
    Layer L[3] = {
        { xTh, xTl, 8,   6, 8,   3, 64,   48,   128,  64, 160, w1, b1, o1H, o1L },
        { o1H, o1L, 128, 5, 128, 7, 640,  640,  512,  32, 161, w2, b2, o2H, o2L },
        { o2H, o2L, 512, 3, 512, 9, 1536, 1536, 1024, 8,  162, w3, b3, o3H, o3L },
    };

    xt_prep_kernel<<<LDT / 256, 256, 0, stream>>>(x, xTh, xTl);
    wtrans_kernel<<<(1024 * 512 + 255) / 256, 256, 0, stream>>>(fw1, fwT1, 1024, 512);
    wtrans_kernel<<<(512 * 128 + 255) / 256, 256, 0, stream>>>(fw2, fwT2, 512, 128);
    wtrans_kernel<<<(128 * 10 + 255) / 256, 256, 0, stream>>>(fw3, fwT3, 128, 10);

    for (int l = 0; l < 3; l++) {
        const Layer& P = L[l];
        int NC = (P.C + 127) / 128;
        int CR = (P.Cpad < 64) ? 64 : P.Cpad;    // row-major stride (zero-padded)
        wtt_prep_kernel<<<(P.Cout * P.Kp64 + 255) / 256, 256, 0, stream>>>(
            P.Wk, WtT, P.Kp64, P.KpValid, P.Cpad - 1, P.shift, (l == 0) ? 6 : P.C, P.Cout);
        sqt_part_kernel<<<dim3(LDT / 256, NC), 256, 0, stream>>>(P.XTh, P.XTl, P.C, sqpart);
        sqt_red_kernel<<<LDT / 256, 256, 0, stream>>>(sqpart, NC, sq);
        // once-per-layer transpose to row-major [point][CR]
        xpose_kernel<<<dim3(LDT / 128, CR / 64), 256, 0, stream>>>(
            P.XTh, P.XTl, P.Cpad, CR, XRh, XRl);
        adj_mfma_kernel<<<dim3(8, 8, BB), 256, 0, stream>>>(XRh, XRl, CR / 64, CR, sq,
                                                            Wbuf, Wpart, diagW);
        reduce_prep_kernel<<<BB * NN / 256, 256, 0, stream>>>(Wpart, diagW, dinv, dinvP, cA1, cA2, cAV);

        // scaled Z0 for the first wgemm's B operand
        scale_sc_kernel<<<(P.Cpad * LDT / 8 + 255) / 256, 256, 0, stream>>>(
            P.XTh, dinv, Z0Sc, P.Cpad * LDT / 8);

        int cT = (P.Cpad + 127) / 128;
        bool sm = (P.Cpad <= 128);               // small-C: 64-row i-tiles, 2x grid
        auto sliceR = [&](int k) -> short* { return Zbuf + (size_t)(k - 1) * P.Cpad * LDT; };
        auto sliceS = [&](int k) -> short* { return ZSc  + (size_t)(k - 1) * P.Cpad * LDT; };
        // Z1 = -dinv .* (W @ Z0sc)
        if (P.K > 2) {
            if (sm) wgemm2_kernel<false, false, true, 64><<<dim3(NN / 64, cT, BB), 512, 0, stream>>>(
                        Wbuf, Z0Sc, cA1, 0.f, (const short*)nullptr, dinv, sliceR(1), sliceS(1), P.Cpad);
            else    wgemm2_kernel<false, false, true, 128><<<dim3(NN / 128, cT, BB), 512, 0, stream>>>(
                        Wbuf, Z0Sc, cA1, 0.f, (const short*)nullptr, dinv, sliceR(1), sliceS(1), P.Cpad);
        } else {
            if (sm) wgemm2_kernel<false, false, false, 64><<<dim3(NN / 64, cT, BB), 512, 0, stream>>>(
                        Wbuf, Z0Sc, cA1, 0.f, (const short*)nullptr, dinv, sliceR(1), (short*)nullptr, P.Cpad);
            else    wgemm2_kernel<false, false, false, 128><<<dim3(NN / 128, cT, BB), 512, 0, stream>>>(
                        Wbuf, Z0Sc, cA1, 0.f, (const short*)nullptr, dinv, sliceR(1), (short*)nullptr, P.Cpad);
        }
        // Zk = -2*dinv .* (W @ Zsc_{k-1}) - Z_{k-2}
        for (int k = 2; k < P.K; k++) {
            const short* prevT = (k == 2) ? P.XTh : sliceR(k - 2);
            if (k < P.K - 1) {
                if (sm) wgemm2_kernel<true, false, true, 64><<<dim3(NN / 64, cT, BB), 512, 0, stream>>>(
                            Wbuf, sliceS(k - 1), cA2, -1.f, prevT, dinv, sliceR(k), sliceS(k), P.Cpad);
                else    wgemm2_kernel<true, false, true, 128><<<dim3(NN / 128, cT, BB), 512, 0, stream>>>(
                            Wbuf, sliceS(k - 1), cA2, -1.f, prevT, dinv, sliceR(k), sliceS(k), P.Cpad);
            } else {
                if (sm) wgemm2_kernel<true, false, false, 64><<<dim3(NN / 64, cT, BB), 512, 0, stream>>>(
                            Wbuf, sliceS(k - 1), cA2, -1.f, prevT, dinv, sliceR(k), (short*)nullptr, P.Cpad);
                else    wgemm2_kernel<true, false, false, 128><<<dim3(NN / 128, cT, BB), 512, 0, stream>>>(
                            Wbuf, sliceS(k - 1), cA2, -1.f, prevT, dinv, sliceR(k), (short*)nullptr, P.Cpad);
            }
        }
        fgemm_mfma_kernel<<<dim3(LDT / 128, P.Cout / 128), 512, 0, stream>>>(
            P.XTh, Zbuf, WtT, P.Kp64, P.KpValid, P.Cpad, P.bk, P.OutH, P.OutL);
        // V = out - dinvP .* (W_nodiag @ (dinvP .* out)); scaled out -> ZSc, V -> Zbuf
        scale_sc_kernel<<<(P.Cout * LDT / 8 + 255) / 256, 256, 0, stream>>>(
            P.OutH, dinvP, ZSc, P.Cout * LDT / 8);
        int cTV = P.Cout / 128;
        if (P.Cout <= 128)
            wgemm2_kernel<true, true, false, 64><<<dim3(NN / 64, cTV, BB), 512, 0, stream>>>(
                Wbuf, ZSc, cAV, 1.f, P.OutH, dinvP, Zbuf, (short*)nullptr, P.Cout);
        else
            wgemm2_kernel<true, true, false, 128><<<dim3(NN / 128, cTV, BB), 512, 0, stream>>>(
                Wbuf, ZSc, cAV, 1.f, P.OutH, dinvP, Zbuf, (short*)nullptr, P.Cout);
        int kChunk = LDT / P.splitk;
        mgemm_mfma_kernel<<<dim3(P.Cout / 128, P.Cout / 128, P.splitk), 256, 0, stream>>>(
            P.OutH, Zbuf, Mpart, P.Cout, kChunk);
        fro1_kernel<<<1024, 256, 0, stream>>>(Mpart, P.Cout * P.Cout, P.splitk, blockSS);
        fro2_kernel<<<1, 256, 0, stream>>>(blockSS, out + P.rIdx);
    }
    pool_kernel<<<16384 / 4, 256, 0, stream>>>(o3H, o3L, pooled);
    fc_kernel<<<(16 * 512 + 3) / 4, 256, 0, stream>>>(pooled, fwT1, fb1, h1, 1024, 512, 1);
    fc_kernel<<<(16 * 128 + 3) / 4, 256, 0, stream>>>(h1, fwT2, fb2, h2, 512, 128, 1);
    fc_kernel<<<(16 * 10 + 3) / 4, 256, 0, stream>>>(h2, fwT3, fb3, out, 128, 10, 0);
}

// Round 15
// 897.079 us; speedup vs baseline: 1.0813x; 1.0259x over previous
//
#include <hip/hip_runtime.h>

#define BB 16
#define NN 1024
#define LDT 16384          // column count of all transposed feature buffers

typedef float4 f4;
typedef __attribute__((ext_vector_type(8))) short bf16x8;
typedef __attribute__((ext_vector_type(4))) float f32x4;

// bf16 pack/unpack (RNE)
__device__ __forceinline__ unsigned f2b1(float f) {
    unsigned u = __builtin_bit_cast(unsigned, f);
    return (u + 0x7fffu + ((u >> 16) & 1u)) >> 16;
}
__device__ __forceinline__ float b2f1(unsigned s) {
    unsigned u = (s & 0xffffu) << 16;
    return __builtin_bit_cast(float, u);
}

// LDS tile element offset, swizzled. Tile is [row][k] = [R][64] shorts.
// g = (row&7) ^ ((row>>3)&7): conflict-free for transpose-writes, row-copies and
// fragment reads, with compile-time register indexing everywhere.
#define SW(r, k) ((r) * 64 + ((k) ^ (((((r) & 7) ^ (((r) >> 3) & 7))) << 3)))

// ---- async global->LDS, 16B per lane. LDS dest = wave-uniform base + lane*16
// (linear); the global source chunk is pre-swizzled so data lands at SW(r,k):
// segment s covers rows 8s..8s+7; lane l -> row 8s+(l>>3), holds chunk
// jc = (l&7) ^ (l>>3) ^ (s&7) (== SW's placement). Reads stay unchanged.
__device__ __forceinline__ void gload16(const unsigned short* g, short* l) {
    __builtin_amdgcn_global_load_lds(
        (const __attribute__((address_space(1))) unsigned int*)g,
        (__attribute__((address_space(3))) unsigned int*)l, 16, 0, 0);
}

__device__ __forceinline__ float wave_sum(float v) {
    #pragma unroll
    for (int m = 32; m >= 1; m >>= 1) v += __shfl_xor(v, m);
    return v;
}
__device__ __forceinline__ float wave_max(float v) {
    #pragma unroll
    for (int m = 32; m >= 1; m >>= 1) v = fmaxf(v, __shfl_xor(v, m));
    return v;
}

// ---- transpose staging (pair-pack): T[r=0..127][c=0..63] = src[(c0+c)*LDT + col_base + r] ----
__device__ __forceinline__ void stage_tr(short* T, const unsigned short* src,
                                         size_t col_base, int c0, int Cvalid, int tid) {
    #pragma unroll
    for (int n = 0; n < 2; n++) {
        int q = n * 256 + tid;
        int p = q >> 4, h = q & 15;
        int cg = c0 + 2 * p;
        uint4 r0 = make_uint4(0, 0, 0, 0), r1 = make_uint4(0, 0, 0, 0);
        if (cg < Cvalid)     r0 = *(const uint4*)&src[(size_t)cg * LDT + col_base + 8 * h];
        if (cg + 1 < Cvalid) r1 = *(const uint4*)&src[(size_t)(cg + 1) * LDT + col_base + 8 * h];
        const unsigned* a0 = (const unsigned*)&r0;
        const unsigned* a1 = (const unsigned*)&r1;
        #pragma unroll
        for (int e = 0; e < 8; e++) {
            unsigned lo = (e & 1) ? (a0[e >> 1] >> 16) : (a0[e >> 1] & 0xffffu);
            unsigned hi = (e & 1) ? (a1[e >> 1] >> 16) : (a1[e >> 1] & 0xffffu);
            int r = 8 * h + e;
            *(unsigned*)&T[SW(r, 2 * p)] = lo | (hi << 16);
        }
    }
}

// ================= input prep =================
__global__ void xt_prep_kernel(const float* __restrict__ x, short* __restrict__ xh,
                               short* __restrict__ xl) {
    int m = blockIdx.x * 256 + threadIdx.x;
    #pragma unroll
    for (int c = 0; c < 8; c++) {
        float v = (c < 6) ? x[(size_t)m * 6 + c] : 0.f;
        unsigned h = f2b1(v);
        unsigned l = f2b1(v - b2f1(h));
        xh[(size_t)c * LDT + m] = (short)h;
        xl[(size_t)c * LDT + m] = (short)l;
    }
}

__global__ void wtt_prep_kernel(const float* __restrict__ Wk, short* __restrict__ WtT,
                                int Kp64, int KpValid, int CpadM1, int shift, int Cin, int Cout) {
    int idx = blockIdx.x * 256 + threadIdx.x;
    if (idx >= Cout * Kp64) return;
    int co = idx / Kp64, kk = idx - co * Kp64;
    int c = kk & CpadM1;
    float val = 0.f;
    if (kk < KpValid && c < Cin)
        val = Wk[((size_t)(kk >> shift) * Cin + c) * Cout + co];
    WtT[(size_t)co * Kp64 + kk] = (short)f2b1(val);
}

// ---- FC weight transpose: WtT[o][k] = Wt[k][o] ----
__global__ void wtrans_kernel(const float* __restrict__ Wt, float* __restrict__ WtT,
                              int K, int O) {
    int idx = blockIdx.x * 256 + threadIdx.x;
    if (idx >= K * O) return;
    int o = idx / K, k = idx - o * K;
    WtT[idx] = Wt[(size_t)k * O + o];
}

// ---- scaled copy: dst[c][m] = bf16( src[c][m] * coeff[m] ) ----
__global__ void scale_sc_kernel(const short* __restrict__ src, const float* __restrict__ coeff,
                                short* __restrict__ dst, int total8) {
    int q = blockIdx.x * 256 + threadIdx.x;
    if (q >= total8) return;
    size_t base = (size_t)q * 8;
    int m8 = (int)(base & (LDT - 1));
    uint4 v = *(const uint4*)&((const unsigned short*)src)[base];
    f4 c0 = *(const f4*)&coeff[m8];
    f4 c1 = *(const f4*)&coeff[m8 + 4];
    const float* cp0 = (const float*)&c0;
    const float* cp1 = (const float*)&c1;
    unsigned* vp = (unsigned*)&v;
    #pragma unroll
    for (int e = 0; e < 4; e++) {
        float se0 = (e < 2) ? cp0[2 * e] : cp1[2 * e - 4];
        float se1 = (e < 2) ? cp0[2 * e + 1] : cp1[2 * e - 3];
        vp[e] = f2b1(b2f1(vp[e]) * se0) | (f2b1(b2f1(vp[e] >> 16) * se1) << 16);
    }
    *(uint4*)&((unsigned short*)dst)[base] = v;
}

// ---- layer-wide transpose: XR[m][c] = XT[c][m], rows padded/zeroed to CR ----
__global__ __launch_bounds__(256)
void xpose_kernel(const short* __restrict__ H, const short* __restrict__ L,
                  int Cvalid, int CR, short* __restrict__ XRh, short* __restrict__ XRl) {
    __shared__ short Th[128 * 64], Tl[128 * 64];
    int tid = threadIdx.x;
    int m0 = blockIdx.x * 128, c0 = blockIdx.y * 64;
    stage_tr(Th, (const unsigned short*)H, m0, c0, Cvalid, tid);
    stage_tr(Tl, (const unsigned short*)L, m0, c0, Cvalid, tid);
    __syncthreads();
    #pragma unroll
    for (int n = 0; n < 4; n++) {
        int q = n * 256 + tid;
        int r = q >> 3, j = q & 7;
        int g = (r & 7) ^ ((r >> 3) & 7);
        *(uint4*)&XRh[(size_t)(m0 + r) * CR + c0 + 8 * j] = *(const uint4*)&Th[r * 64 + 8 * (j ^ g)];
        *(uint4*)&XRl[(size_t)(m0 + r) * CR + c0 + 8 * j] = *(const uint4*)&Tl[r * 64 + 8 * (j ^ g)];
    }
}

// ================= squared norms from hi/lo (partial over 128-c chunks) =================
__global__ void sqt_part_kernel(const short* __restrict__ H, const short* __restrict__ L,
                                int C, float* __restrict__ dst) {
    int m = blockIdx.x * 256 + threadIdx.x;
    int cb = blockIdx.y * 128;
    int ce = min(cb + 128, C);
    const unsigned short* Hp = (const unsigned short*)H;
    const unsigned short* Lp = (const unsigned short*)L;
    float s = 0.f;
    for (int c = cb; c < ce; c++) {
        float v = b2f1(Hp[(size_t)c * LDT + m]) + b2f1(Lp[(size_t)c * LDT + m]);
        s += v * v;
    }
    dst[(size_t)blockIdx.y * LDT + m] = s;
}
__global__ void sqt_red_kernel(const float* __restrict__ part, int NC, float* __restrict__ sq) {
    int m = blockIdx.x * 256 + threadIdx.x;
    float s = 0.f;
    for (int y = 0; y < NC; y++) s += part[(size_t)y * LDT + m];
    sq[m] = s;
}

// ====== adjacency + fused row-sum partials: W[b][j][i] = exp(2G - sq_i - sq_j) ======
// 4 waves; wave tile 64(j) x 64(i). Staging via global_load_lds from row-major XR.
// Off-diag partial sums -> Wpart; diag -> diagW.
__global__ __launch_bounds__(256)
void adj_mfma_kernel(const short* __restrict__ XRh, const short* __restrict__ XRl,
                     int ck64, int CR, const float* __restrict__ sq,
                     short* __restrict__ Wb, float* __restrict__ Wpart,
                     float* __restrict__ diagW) {
    __shared__ short Ah[128 * 64], Al[128 * 64], Bh[128 * 64], Bl[128 * 64];
    __shared__ float jpart[128][2];
    int tid = threadIdx.x, lane = tid & 63, w = tid >> 6;
    int wj = w >> 1, wi = w & 1;
    int b = blockIdx.z, i0 = blockIdx.x * 128, j0 = blockIdx.y * 128;
    size_t bo = (size_t)b * NN;
    f32x4 acc[4][4] = {};
    const unsigned short* Hp = (const unsigned short*)XRh;
    const unsigned short* Lp = (const unsigned short*)XRl;
    // per-lane pre-swizzled source offsets for the 4 segments this wave stages per tile
    int rr = lane >> 3, jj = lane & 7;
    size_t offI[4], offJ[4];
    #pragma unroll
    for (int m = 0; m < 4; m++) {
        int s = w + m * 4;
        int jc = jj ^ rr ^ (s & 7);
        offI[m] = (size_t)(bo + i0 + 8 * s + rr) * CR + 8 * jc;
        offJ[m] = (size_t)(bo + j0 + 8 * s + rr) * CR + 8 * jc;
    }
    for (int t = 0; t < ck64; t++) {
        int c0 = t * 64;
        #pragma unroll
        for (int m = 0; m < 4; m++) {
            int s512 = (w + m * 4) * 512;
            gload16(Hp + offI[m] + c0, Ah + s512);
            gload16(Lp + offI[m] + c0, Al + s512);
            gload16(Hp + offJ[m] + c0, Bh + s512);
            gload16(Lp + offJ[m] + c0, Bl + s512);
        }
        __syncthreads();
        int la = lane & 15;
        #pragma unroll
        for (int ks = 0; ks < 2; ks++) {
            int kb = ks * 32 + (lane >> 4) * 8;
            bf16x8 jh[4], jl[4], ih[4], il[4];
            #pragma unroll
            for (int f = 0; f < 4; f++) {
                int jr = wj * 64 + f * 16 + la;
                jh[f] = *(const bf16x8*)&Bh[SW(jr, kb)];
                jl[f] = *(const bf16x8*)&Bl[SW(jr, kb)];
                int ir = wi * 64 + f * 16 + la;
                ih[f] = *(const bf16x8*)&Ah[SW(ir, kb)];
                il[f] = *(const bf16x8*)&Al[SW(ir, kb)];
            }
            #pragma unroll
            for (int fq = 0; fq < 4; fq++)
                #pragma unroll
                for (int fi = 0; fi < 4; fi++) {
                    acc[fq][fi] = __builtin_amdgcn_mfma_f32_16x16x32_bf16(jh[fq], ih[fi], acc[fq][fi], 0, 0, 0);
                    acc[fq][fi] = __builtin_amdgcn_mfma_f32_16x16x32_bf16(jh[fq], il[fi], acc[fq][fi], 0, 0, 0);
                    acc[fq][fi] = __builtin_amdgcn_mfma_f32_16x16x32_bf16(jl[fq], ih[fi], acc[fq][fi], 0, 0, 0);
                }
        }
        __syncthreads();
    }
    const float* sqb = sq + bo;
    unsigned short* Wout = (unsigned short*)Wb + bo * NN;
    float si_[4];
    int iloc[4];
    #pragma unroll
    for (int fi = 0; fi < 4; fi++) {
        iloc[fi] = i0 + wi * 64 + fi * 16 + (lane & 15);
        si_[fi] = sqb[iloc[fi]];
    }
    #pragma unroll
    for (int fq = 0; fq < 4; fq++) {
        int jb = j0 + wj * 64 + fq * 16 + (lane >> 4) * 4;
        #pragma unroll
        for (int r = 0; r < 4; r++) {
            int j = jb + r;
            float sj = sqb[j];
            float p = 0.f;
            #pragma unroll
            for (int fi = 0; fi < 4; fi++) {
                float val = __expf(2.f * ((const float*)&acc[fq][fi])[r] - si_[fi] - sj);
                Wout[(size_t)j * NN + iloc[fi]] = (unsigned short)f2b1(val);
                if (iloc[fi] == j) diagW[bo + j] = val;
                else p += val;
            }
            p += __shfl_xor(p, 1); p += __shfl_xor(p, 2);
            p += __shfl_xor(p, 4); p += __shfl_xor(p, 8);
            if ((lane & 15) == 0)
                jpart[wj * 64 + fq * 16 + (lane >> 4) * 4 + r][wi] = p;
        }
    }
    __syncthreads();
    if (tid < 128)
        Wpart[(size_t)blockIdx.x * (BB * NN) + bo + j0 + tid] = jpart[tid][0] + jpart[tid][1];
}

// ====== reduce partials -> coefficient vectors ======
__global__ void reduce_prep_kernel(const float* __restrict__ Wpart, const float* __restrict__ diagW,
                                   float* dinv, float* dinvP, float* cA1, float* cA2, float* cAV) {
    int idx = blockIdx.x * 256 + threadIdx.x;    // [0, 16384)
    float s = 0.f;
    #pragma unroll
    for (int x = 0; x < 8; x++) s += Wpart[(size_t)x * (BB * NN) + idx];
    float d = diagW[idx];
    float dv = rsqrtf(s + d);    // full sum (incl diag)
    float dp = rsqrtf(s);        // exact off-diag sum (no cancellation)
    dinv[idx] = dv; dinvP[idx] = dp;
    cA1[idx] = -dv; cA2[idx] = -2.f * dv; cAV[idx] = -dp;
}

// ====== W-GEMM (8 waves): Dst[c][i] = cA_i * sum_j W[i][j]*Bsc[c][j] (+ prevSign*Prev[c][i]) ======
// Double-buffered LDS, single barrier per k-tile: STAGE(t+1) issues before tile-t
// MFMAs so load latency hides under compute (guide T3/T4 minimum-2-phase recipe).
// XB = i-tile rows (128 or 64). Per-element math identical to the 2-barrier version.
template<bool HAS_PREV, bool SKIP_DIAG, bool WRITE_SC, int XB>
__global__ __launch_bounds__(512)
void wgemm2_kernel(const short* __restrict__ W, const short* __restrict__ Bsc,
                   const float* __restrict__ cAvec, float prevSign,
                   const short* __restrict__ PrevT, const float* __restrict__ scVec,
                   short* __restrict__ DstT, short* __restrict__ DstSc, int Cvalid) {
    __shared__ short As[2][XB * 64], Bs[2][128 * 64];
    constexpr int NFI = XB / 64;                 // i-frags per wave (2 or 1)
    int tid = threadIdx.x, lane = tid & 63, w = tid >> 6;
    int wcc = w >> 2, wii = w & 3;               // wave tile: 64 c x XB/4 i
    int b = blockIdx.z, i0 = blockIdx.x * XB, c0 = blockIdx.y * 128;
    size_t bo = (size_t)b * NN;
    const unsigned short* Wp = (const unsigned short*)W + bo * NN;
    const unsigned short* Bp = (const unsigned short*)Bsc;
    int rr = lane >> 3, jj = lane & 7;
    int jc = jj ^ rr ^ (w & 7);                  // (w+8)&7 == w&7
    const unsigned short* aR0 = Wp + (size_t)(i0 + 8 * w + rr) * NN + 8 * jc;
    const unsigned short* aR1 = Wp + (size_t)(i0 + 8 * ((XB == 128) ? w + 8 : w) + rr) * NN + 8 * jc;
    const unsigned short* bR0 = Bp + (size_t)(c0 + 8 * w + rr) * LDT + bo + 8 * jc;
    const unsigned short* bR1 = Bp + (size_t)(c0 + 8 * (w + 8) + rr) * LDT + bo + 8 * jc;
    int aO0 = w * 512;
    int aO1 = ((XB == 128) ? w + 8 : w) * 512;
    int bO0 = w * 512, bO1 = (w + 8) * 512;
    auto STAGE = [&](int k0, int buf) {
        gload16(aR0 + k0, As[buf] + aO0);
        if (XB == 128) gload16(aR1 + k0, As[buf] + aO1);
        gload16(bR0 + k0, Bs[buf] + bO0);
        gload16(bR1 + k0, Bs[buf] + bO1);
    };
    f32x4 acc[4][NFI] = {};
    STAGE(0, 0);
    __syncthreads();                              // drains vmcnt; tile 0 published
    int cur = 0;
    for (int t = 0; t < NN / 64; t++) {
        int k0 = t * 64;
        bool more = (t + 1 < NN / 64);
        if (more) STAGE(k0 + 64, cur ^ 1);        // prefetch next tile (other buffer)
        if (SKIP_DIAG) {
            if (k0 >= i0 && k0 < i0 + XB) {       // diag band intersects this k-tile
                if (tid < 64) As[cur][SW((k0 - i0) + tid, tid)] = 0;
                __syncthreads();                  // publish patch (rare, block-uniform)
            }
        }
        int la = lane & 15;
        #pragma unroll
        for (int ks = 0; ks < 2; ks++) {
            int kb = ks * 32 + (lane >> 4) * 8;
            bf16x8 ac[4], bi[NFI];
            #pragma unroll
            for (int f = 0; f < 4; f++) ac[f] = *(const bf16x8*)&Bs[cur][SW(wcc * 64 + f * 16 + la, kb)];
            #pragma unroll
            for (int f = 0; f < NFI; f++) bi[f] = *(const bf16x8*)&As[cur][SW(wii * (XB / 4) + f * 16 + la, kb)];
            #pragma unroll
            for (int fq = 0; fq < 4; fq++)
                #pragma unroll
                for (int fi = 0; fi < NFI; fi++)
                    acc[fq][fi] = __builtin_amdgcn_mfma_f32_16x16x32_bf16(ac[fq], bi[fi], acc[fq][fi], 0, 0, 0);
        }
        if (more) __syncthreads();                // joins readers of cur; drains next stage
        cur ^= 1;
    }
    const unsigned short* Pp = (const unsigned short*)PrevT;
    unsigned short* Dp = (unsigned short*)DstT;
    unsigned short* Sp = (unsigned short*)DstSc;
    #pragma unroll
    for (int fi = 0; fi < NFI; fi++) {
        int i = i0 + wii * (XB / 4) + fi * 16 + (lane & 15);
        float ca = cAvec[bo + i];
        float sc = WRITE_SC ? scVec[bo + i] : 0.f;
        #pragma unroll
        for (int fq = 0; fq < 4; fq++) {
            int cb = c0 + wcc * 64 + fq * 16 + (lane >> 4) * 4;
            const float* av = (const float*)&acc[fq][fi];
            #pragma unroll
            for (int r = 0; r < 4; r++) {
                int c = cb + r;
                if (c < Cvalid) {
                    float v = ca * av[r];
                    if (HAS_PREV) v += prevSign * b2f1(Pp[(size_t)c * LDT + bo + i]);
                    Dp[(size_t)c * LDT + bo + i] = (unsigned short)f2b1(v);
                    if (WRITE_SC) Sp[(size_t)c * LDT + bo + i] = (unsigned short)f2b1(v * sc);
                }
            }
        }
    }
}

// ====== feature GEMM (8 waves): Out[co][m] = relu(sum_kk Zcat[m][kk]*Wt[kk][co] + bias) ======
// Double-buffered LDS, single barrier per k-tile: loadA(t+1)+gloadB(t+1) issue
// before tile-t MFMAs; unpack(t+1) lands in the idle buffer after MFMAs.
__global__ __launch_bounds__(512)
void fgemm_mfma_kernel(const short* __restrict__ A0T, const short* __restrict__ ZrT,
                       const short* __restrict__ WtT, int Kp64, int KpValid, int Cpad,
                       const float* __restrict__ bias,
                       short* __restrict__ OutH, short* __restrict__ OutL) {
    __shared__ short As[2][128 * 64], Bs[2][128 * 64];
    int tid = threadIdx.x, lane = tid & 63, w = tid >> 6;
    int wco = w >> 2, wm = w & 3;                // wave tile: 64 co x 32 m
    int m0 = blockIdx.x * 128, co0 = blockIdx.y * 128;
    const unsigned short* A0 = (const unsigned short*)A0T;
    const unsigned short* Zr = (const unsigned short*)ZrT;
    const unsigned short* Wt = (const unsigned short*)WtT;
    // B staging addresses (gload16, row stride Kp64)
    int rr = lane >> 3, jj = lane & 7;
    int jcB = jj ^ rr ^ (w & 7);
    const unsigned short* bB0 = Wt + (size_t)(co0 + 8 * w + rr) * Kp64 + 8 * jcB;
    const unsigned short* bB1 = Wt + (size_t)(co0 + 8 * (w + 8) + rr) * Kp64 + 8 * jcB;
    int bO0 = w * 512, bO1 = (w + 8) * 512;
    int p = tid >> 4, h = tid & 15;
    uint4 ra0, ra1;
    auto loadA = [&](int kk0) {
        int kg0 = kk0 + 2 * p;
        ra0 = make_uint4(0, 0, 0, 0); ra1 = make_uint4(0, 0, 0, 0);
        if (kg0 < KpValid) {
            const unsigned short* s0 = (kg0 < Cpad) ? (A0 + (size_t)kg0 * LDT)
                                                    : (Zr + (size_t)(kg0 - Cpad) * LDT);
            ra0 = *(const uint4*)&s0[m0 + 8 * h];
        }
        if (kg0 + 1 < KpValid) {
            int kg1 = kg0 + 1;
            const unsigned short* s1 = (kg1 < Cpad) ? (A0 + (size_t)kg1 * LDT)
                                                    : (Zr + (size_t)(kg1 - Cpad) * LDT);
            ra1 = *(const uint4*)&s1[m0 + 8 * h];
        }
    };
    auto unpackA = [&](int buf) {                // held A regs -> LDS, static e indexing
        const unsigned* a0 = (const unsigned*)&ra0;
        const unsigned* a1 = (const unsigned*)&ra1;
        #pragma unroll
        for (int e = 0; e < 8; e++) {
            unsigned lo = (e & 1) ? (a0[e >> 1] >> 16) : (a0[e >> 1] & 0xffffu);
            unsigned hi = (e & 1) ? (a1[e >> 1] >> 16) : (a1[e >> 1] & 0xffffu);
            *(unsigned*)&As[buf][SW(8 * h + e, 2 * p)] = lo | (hi << 16);
        }
    };
    f32x4 acc[4][2] = {};
    loadA(0);
    gload16(bB0, Bs[0] + bO0);
    gload16(bB1, Bs[0] + bO1);
    unpackA(0);
    __syncthreads();                              // drains B0; publishes As[0]
    int cur = 0;
    for (int kk0 = 0; kk0 < Kp64; kk0 += 64) {
        bool more = (kk0 + 64 < Kp64);
        if (more) {
            loadA(kk0 + 64);                      // issue next A reg loads
            gload16(bB0 + kk0 + 64, Bs[cur ^ 1] + bO0);   // next B -> other buffer
            gload16(bB1 + kk0 + 64, Bs[cur ^ 1] + bO1);
        }
        int la = lane & 15;
        #pragma unroll
        for (int ks = 0; ks < 2; ks++) {
            int kb = ks * 32 + (lane >> 4) * 8;
            bf16x8 ac[4], bm[2];
            #pragma unroll
            for (int f = 0; f < 4; f++) ac[f] = *(const bf16x8*)&Bs[cur][SW(wco * 64 + f * 16 + la, kb)];
            #pragma unroll
            for (int f = 0; f < 2; f++) bm[f] = *(const bf16x8*)&As[cur][SW(wm * 32 + f * 16 + la, kb)];
            #pragma unroll
            for (int fq = 0; fq < 4; fq++)
                #pragma unroll
                for (int fi = 0; fi < 2; fi++)
                    acc[fq][fi] = __builtin_amdgcn_mfma_f32_16x16x32_bf16(ac[fq], bm[fi], acc[fq][fi], 0, 0, 0);
        }
        if (more) {
            unpackA(cur ^ 1);                     // next A -> other buffer (regs arrived under MFMAs)
            __syncthreads();                      // joins readers of cur; drains next B stage
        }
        cur ^= 1;
    }
    unsigned short* OH = (unsigned short*)OutH;
    unsigned short* OL = (unsigned short*)OutL;
    #pragma unroll
    for (int fi = 0; fi < 2; fi++) {
        int m = m0 + wm * 32 + fi * 16 + (lane & 15);
        #pragma unroll
        for (int fq = 0; fq < 4; fq++) {
            int cb = co0 + wco * 64 + fq * 16 + (lane >> 4) * 4;
            const float* av = (const float*)&acc[fq][fi];
            #pragma unroll
            for (int r = 0; r < 4; r++) {
                int co = cb + r;
                float v = av[r] + bias[co];
                v = v > 0.f ? v : 0.f;
                unsigned ph = f2b1(v);
                unsigned pl = f2b1(v - b2f1(ph));
                OH[(size_t)co * LDT + m] = (unsigned short)ph;
                OL[(size_t)co * LDT + m] = (unsigned short)pl;
            }
        }
    }
}

// ====== M partials: Mpart[z][cj][ci] = sum_{m in chunk} XT[ci][m]*VT[cj][m] ======
__global__ __launch_bounds__(256)
void mgemm_mfma_kernel(const short* __restrict__ XT, const short* __restrict__ VT,
                       float* __restrict__ Mpart, int Cout, int kChunk) {
    __shared__ short As[128 * 64], Bs[128 * 64];
    int tid = threadIdx.x, lane = tid & 63, w = tid >> 6;
    int wcj = w >> 1, wci = w & 1;
    int ci0 = blockIdx.x * 128, cj0 = blockIdx.y * 128;
    int kStart = blockIdx.z * kChunk;
    const unsigned short* Xp = (const unsigned short*)XT + (size_t)ci0 * LDT;
    const unsigned short* Vp = (const unsigned short*)VT + (size_t)cj0 * LDT;
    // hoisted per-lane source addresses: 4 waves x 4 segments each
    int rr = lane >> 3, jj = lane & 7;
    const unsigned short* aB[4];
    const unsigned short* bB[4];
    short* aL[4]; short* bL[4];
    #pragma unroll
    for (int n = 0; n < 4; n++) {
        int s = w + n * 4;
        int jc = jj ^ rr ^ (s & 7);
        aB[n] = Xp + (size_t)(8 * s + rr) * LDT + 8 * jc;
        bB[n] = Vp + (size_t)(8 * s + rr) * LDT + 8 * jc;
        aL[n] = As + s * 512; bL[n] = Bs + s * 512;
    }
    f32x4 acc[4][4] = {};
    for (int k0 = kStart; k0 < kStart + kChunk; k0 += 64) {
        #pragma unroll
        for (int n = 0; n < 4; n++) {
            gload16(aB[n] + k0, aL[n]);
            gload16(bB[n] + k0, bL[n]);
        }
        __syncthreads();
        int la = lane & 15;
        #pragma unroll
        for (int ks = 0; ks < 2; ks++) {
            int kb = ks * 32 + (lane >> 4) * 8;
            bf16x8 aj[4], bi[4];
            #pragma unroll
            for (int f = 0; f < 4; f++) {
                aj[f] = *(const bf16x8*)&Bs[SW(wcj * 64 + f * 16 + la, kb)];   // cj frags
                bi[f] = *(const bf16x8*)&As[SW(wci * 64 + f * 16 + la, kb)];   // ci frags
            }
            #pragma unroll
            for (int fq = 0; fq < 4; fq++)
                #pragma unroll
                for (int fi = 0; fi < 4; fi++)
                    acc[fq][fi] = __builtin_amdgcn_mfma_f32_16x16x32_bf16(aj[fq], bi[fi], acc[fq][fi], 0, 0, 0);
        }
        __syncthreads();
    }
    float* pt = Mpart + (size_t)blockIdx.z * Cout * Cout;
    #pragma unroll
    for (int fq = 0; fq < 4; fq++) {
        int cjb = cj0 + wcj * 64 + fq * 16 + (lane >> 4) * 4;
        #pragma unroll
        for (int fi = 0; fi < 4; fi++) {
            int ci = ci0 + wci * 64 + fi * 16 + (lane & 15);
            const float* av = (const float*)&acc[fq][fi];
            #pragma unroll
            for (int r = 0; r < 4; r++)
                pt[(size_t)(cjb + r) * Cout + ci] = av[r];
        }
    }
}

// ================= Frobenius norm of summed split-K partials (deterministic) =================
__global__ void fro1_kernel(const float* __restrict__ part, int nElem, int splitk,
                            float* __restrict__ blockSS) {
    int tid = threadIdx.x;
    float ss = 0.f;
    for (int idx = blockIdx.x * 256 + tid; idx < nElem; idx += 1024 * 256) {
        float s = 0.f;
        for (int z = 0; z < splitk; z++) s += part[(size_t)z * nElem + idx];
        ss += s * s;
    }
    __shared__ float red[256];
    red[tid] = ss; __syncthreads();
    for (int m = 128; m >= 1; m >>= 1) { if (tid < m) red[tid] += red[tid + m]; __syncthreads(); }
    if (tid == 0) blockSS[blockIdx.x] = red[0];
}
__global__ void fro2_kernel(const float* __restrict__ blockSS, float* __restrict__ outp) {
    int tid = threadIdx.x;
    float s = 0.f;
    for (int i = tid; i < 1024; i += 256) s += blockSS[i];
    __shared__ float red[256];
    red[tid] = s; __syncthreads();
    for (int m = 128; m >= 1; m >>= 1) { if (tid < m) red[tid] += red[tid + m]; __syncthreads(); }
    if (tid == 0) *outp = sqrtf(red[0]);
}

// ================= max-pool over points: one wave per (b,co) row, coalesced =================
__global__ void pool_kernel(const short* __restrict__ H, const short* __restrict__ L,
                            float* __restrict__ out) {
    int wave = threadIdx.x >> 6, lane = threadIdx.x & 63;
    int r = blockIdx.x * 4 + wave;             // [0, 16384): r = co*16 + b
    int co = r >> 4, b = r & 15;
    const unsigned short* h = (const unsigned short*)H + (size_t)co * LDT + b * NN;
    const unsigned short* l = (const unsigned short*)L + (size_t)co * LDT + b * NN;
    float m = -1e30f;
    #pragma unroll
    for (int it = 0; it < 2; it++) {
        int n8 = (it * 64 + lane) * 8;
        uint4 vh = *(const uint4*)&h[n8];
        uint4 vl = *(const uint4*)&l[n8];
        const unsigned* hp = (const unsigned*)&vh;
        const unsigned* lp = (const unsigned*)&vl;
        #pragma unroll
        for (int e = 0; e < 4; e++) {
            m = fmaxf(m, b2f1(hp[e]) + b2f1(lp[e]));
            m = fmaxf(m, b2f1(hp[e] >> 16) + b2f1(lp[e] >> 16));
        }
    }
    m = wave_max(m);
    if (lane == 0) out[b * 1024 + co] = m;
}

// ================= small FC: one wave per (b,o) output, lanes stride K (coalesced) =================
__global__ void fc_kernel(const float* __restrict__ in, const float* __restrict__ WtT,
                          const float* __restrict__ bias, float* __restrict__ out,
                          int K, int O, int doRelu) {
    int wave = threadIdx.x >> 6, lane = threadIdx.x & 63;
    int idx = blockIdx.x * 4 + wave;           // [0, 16*O)
    if (idx >= 16 * O) return;
    int b = idx / O, o = idx - b * O;
    const float* ib = in + (size_t)b * K;
    const float* wr = WtT + (size_t)o * K;
    float s = 0.f;
    for (int k = lane * 4; k < K; k += 256) {
        f4 a = *(const f4*)&ib[k];
        f4 wv = *(const f4*)&wr[k];
        s += a.x * wv.x + a.y * wv.y + a.z * wv.z + a.w * wv.w;
    }
    s = wave_sum(s);
    if (lane == 0) {
        s += bias[o];
        if (doRelu) s = fmaxf(s, 0.f);
        out[(size_t)b * O + o] = s;
    }
}

extern "C" void kernel_launch(void* const* d_in, const int* in_sizes, int n_in,
                              void* d_out, int out_size, void* d_ws, size_t ws_size,
                              hipStream_t stream) {
    const float* x   = (const float*)d_in[0];
    const float* w1  = (const float*)d_in[4];
    const float* b1  = (const float*)d_in[5];
    const float* w2  = (const float*)d_in[6];
    const float* b2  = (const float*)d_in[7];
    const float* w3  = (const float*)d_in[8];
    const float* b3  = (const float*)d_in[9];
    const float* fw1 = (const float*)d_in[10];
    const float* fb1 = (const float*)d_in[11];
    const float* fw2 = (const float*)d_in[12];
    const float* fb2 = (const float*)d_in[13];
    const float* fw3 = (const float*)d_in[14];
    const float* fb3 = (const float*)d_in[15];
    float* out = (float*)d_out;

    char* ws = (char*)d_ws;
    size_t off = 0;
    auto alloc = [&](size_t bytes) -> void* {
        void* p = ws + off; off += (bytes + 255) & ~(size_t)255; return p;
    };
    short* Wbuf = (short*)alloc((size_t)BB * NN * NN * 2);   // 32 MiB; Mpart aliases after V-step
    short* Zbuf = (short*)alloc((size_t)1024 * LDT * 2);     // 32 MiB raw Z slices; V output later
    short* ZSc  = (short*)alloc((size_t)1024 * LDT * 2);     // 32 MiB scaled Z slices / scaled Out (V)
    short* Z0Sc = (short*)alloc((size_t)512 * LDT * 2);      // 16 MiB scaled Z0 (first wgemm B)
    short* XRh  = (short*)alloc((size_t)512 * LDT * 2);      // 16 MiB row-major X (hi)
    short* XRl  = (short*)alloc((size_t)512 * LDT * 2);      // 16 MiB row-major X (lo)
    short* o1H  = (short*)alloc((size_t)128 * LDT * 2);
    short* o1L  = (short*)alloc((size_t)128 * LDT * 2);
    short* o2H  = (short*)alloc((size_t)512 * LDT * 2);
    short* o2L  = (short*)alloc((size_t)512 * LDT * 2);
    short* o3H  = (short*)alloc((size_t)1024 * LDT * 2);
    short* o3L  = (short*)alloc((size_t)1024 * LDT * 2);
    short* xTh  = (short*)alloc((size_t)8 * LDT * 2);
    short* xTl  = (short*)alloc((size_t)8 * LDT * 2);
    short* WtT  = (short*)alloc((size_t)1024 * 1536 * 2);
    float* fwT1 = (float*)alloc((size_t)512 * 1024 * 4);
    float* fwT2 = (float*)alloc((size_t)128 * 512 * 4);
    float* fwT3 = (float*)alloc((size_t)10 * 128 * 4);
    float* sqpart = (float*)alloc((size_t)8 * LDT * 4);
    float* Wpart  = (float*)alloc((size_t)8 * BB * NN * 4);
    float* diagW  = (float*)alloc(BB * NN * 4);
    float* sq    = (float*)alloc(BB * NN * 4);
    float* dinv  = (float*)alloc(BB * NN * 4);
    float* dinvP = (float*)alloc(BB * NN * 4);
    float* cA1   = (float*)alloc(BB * NN * 4);
    float* cA2   = (float*)alloc(BB * NN * 4);
    float* cAV   = (float*)alloc(BB * NN * 4);
    float* pooled= (float*)alloc(BB * 1024 * 4);
    float* h1    = (float*)alloc(BB * 512 * 4);
    float* h2    = (float*)alloc(BB * 128 * 4);
    float* blockSS = (float*)alloc(1024 * 4);
    float* Mpart = (float*)Wbuf;      // alias: W dead after V-step
    (void)ws_size; (void)in_sizes; (void)n_in; (void)out_size;

    struct Layer {
        const short *XTh, *XTl;       // input features (transposed hi/lo)
        int C, K, Cpad, shift, Kp64, KpValid, Cout, splitk, rIdx;
        const float *Wk, *bk;
        short *OutH, *OutL;
    };
    Layer L[3] = {
        { xTh, xTl, 8,   6, 8,   3, 64,   48,   128,  64, 160, w1, b1, o1H, o1L },
        { o1H, o1L, 128, 5, 128, 7, 640,  640,  512,  32, 161, w2, b2, o2H, o2L },
        { o2H, o2L, 512, 3, 512, 9, 1536, 1536, 1024, 8,  162, w3, b3, o3H, o3L },
    };

    xt_prep_kernel<<<LDT / 256, 256, 0, stream>>>(x, xTh, xTl);
    wtrans_kernel<<<(1024 * 512 + 255) / 256, 256, 0, stream>>>(fw1, fwT1, 1024, 512);
    wtrans_kernel<<<(512 * 128 + 255) / 256, 256, 0, stream>>>(fw2, fwT2, 512, 128);
    wtrans_kernel<<<(128 * 10 + 255) / 256, 256, 0, stream>>>(fw3, fwT3, 128, 10);

    for (int l = 0; l < 3; l++) {
        const Layer& P = L[l];
        int NC = (P.C + 127) / 128;
        int CR = (P.Cpad < 64) ? 64 : P.Cpad;    // row-major stride (zero-padded)
        wtt_prep_kernel<<<(P.Cout * P.Kp64 + 255) / 256, 256, 0, stream>>>(
            P.Wk, WtT, P.Kp64, P.KpValid, P.Cpad - 1, P.shift, (l == 0) ? 6 : P.C, P.Cout);
        sqt_part_kernel<<<dim3(LDT / 256, NC), 256, 0, stream>>>(P.XTh, P.XTl, P.C, sqpart);
        sqt_red_kernel<<<LDT / 256, 256, 0, stream>>>(sqpart, NC, sq);
        // once-per-layer transpose to row-major [point][CR]
        xpose_kernel<<<dim3(LDT / 128, CR / 64), 256, 0, stream>>>(
            P.XTh, P.XTl, P.Cpad, CR, XRh, XRl);
        adj_mfma_kernel<<<dim3(8, 8, BB), 256, 0, stream>>>(XRh, XRl, CR / 64, CR, sq,
                                                            Wbuf, Wpart, diagW);
        reduce_prep_kernel<<<BB * NN / 256, 256, 0, stream>>>(Wpart, diagW, dinv, dinvP, cA1, cA2, cAV);

        // scaled Z0 for the first wgemm's B operand
        scale_sc_kernel<<<(P.Cpad * LDT / 8 + 255) / 256, 256, 0, stream>>>(
            P.XTh, dinv, Z0Sc, P.Cpad * LDT / 8);

        int cT = (P.Cpad + 127) / 128;
        bool sm = (P.Cpad <= 128);               // small-C: 64-row i-tiles, 2x grid
        auto sliceR = [&](int k) -> short* { return Zbuf + (size_t)(k - 1) * P.Cpad * LDT; };
        auto sliceS = [&](int k) -> short* { return ZSc  + (size_t)(k - 1) * P.Cpad * LDT; };
        // Z1 = -dinv .* (W @ Z0sc)
        if (P.K > 2) {
            if (sm) wgemm2_kernel<false, false, true, 64><<<dim3(NN / 64, cT, BB), 512, 0, stream>>>(
                        Wbuf, Z0Sc, cA1, 0.f, (const short*)nullptr, dinv, sliceR(1), sliceS(1), P.Cpad);
            else    wgemm2_kernel<false, false, true, 128><<<dim3(NN / 128, cT, BB), 512, 0, stream>>>(
                        Wbuf, Z0Sc, cA1, 0.f, (const short*)nullptr, dinv, sliceR(1), sliceS(1), P.Cpad);
        } else {
            if (sm) wgemm2_kernel<false, false, false, 64><<<dim3(NN / 64, cT, BB), 512, 0, stream>>>(
                        Wbuf, Z0Sc, cA1, 0.f, (const short*)nullptr, dinv, sliceR(1), (short*)nullptr, P.Cpad);
            else    wgemm2_kernel<false, false, false, 128><<<dim3(NN / 128, cT, BB), 512, 0, stream>>>(
                        Wbuf, Z0Sc, cA1, 0.f, (const short*)nullptr, dinv, sliceR(1), (short*)nullptr, P.Cpad);
        }
        // Zk = -2*dinv .* (W @ Zsc_{k-1}) - Z_{k-2}
        for (int k = 2; k < P.K; k++) {
            const short* prevT = (k == 2) ? P.XTh : sliceR(k - 2);
            if (k < P.K - 1) {
                if (sm) wgemm2_kernel<true, false, true, 64><<<dim3(NN / 64, cT, BB), 512, 0, stream>>>(
                            Wbuf, sliceS(k - 1), cA2, -1.f, prevT, dinv, sliceR(k), sliceS(k), P.Cpad);
                else    wgemm2_kernel<true, false, true, 128><<<dim3(NN / 128, cT, BB), 512, 0, stream>>>(
                            Wbuf, sliceS(k - 1), cA2, -1.f, prevT, dinv, sliceR(k), sliceS(k), P.Cpad);
            } else {
                if (sm) wgemm2_kernel<true, false, false, 64><<<dim3(NN / 64, cT, BB), 512, 0, stream>>>(
                            Wbuf, sliceS(k - 1), cA2, -1.f, prevT, dinv, sliceR(k), (short*)nullptr, P.Cpad);
                else    wgemm2_kernel<true, false, false, 128><<<dim3(NN / 128, cT, BB), 512, 0, stream>>>(
                            Wbuf, sliceS(k - 1), cA2, -1.f, prevT, dinv, sliceR(k), (short*)nullptr, P.Cpad);
            }
        }
        fgemm_mfma_kernel<<<dim3(LDT / 128, P.Cout / 128), 512, 0, stream>>>(
            P.XTh, Zbuf, WtT, P.Kp64, P.KpValid, P.Cpad, P.bk, P.OutH, P.OutL);
        // V = out - dinvP .* (W_nodiag @ (dinvP .* out)); scaled out -> ZSc, V -> Zbuf
        scale_sc_kernel<<<(P.Cout * LDT / 8 + 255) / 256, 256, 0, stream>>>(
            P.OutH, dinvP, ZSc, P.Cout * LDT / 8);
        int cTV = P.Cout / 128;
        if (P.Cout <= 128)
            wgemm2_kernel<true, true, false, 64><<<dim3(NN / 64, cTV, BB), 512, 0, stream>>>(
                Wbuf, ZSc, cAV, 1.f, P.OutH, dinvP, Zbuf, (short*)nullptr, P.Cout);
        else
            wgemm2_kernel<true, true, false, 128><<<dim3(NN / 128, cTV, BB), 512, 0, stream>>>(
                Wbuf, ZSc, cAV, 1.f, P.OutH, dinvP, Zbuf, (short*)nullptr, P.Cout);
        int kChunk = LDT / P.splitk;
        mgemm_mfma_kernel<<<dim3(P.Cout / 128, P.Cout / 128, P.splitk), 256, 0, stream>>>(
            P.OutH, Zbuf, Mpart, P.Cout, kChunk);
        fro1_kernel<<<1024, 256, 0, stream>>>(Mpart, P.Cout * P.Cout, P.splitk, blockSS);
        fro2_kernel<<<1, 256, 0, stream>>>(blockSS, out + P.rIdx);
    }
    pool_kernel<<<16384 / 4, 256, 0, stream>>>(o3H, o3L, pooled);
    fc_kernel<<<(16 * 512 + 3) / 4, 256, 0, stream>>>(pooled, fwT1, fb1, h1, 1024, 512, 1);
    fc_kernel<<<(16 * 128 + 3) / 4, 256, 0, stream>>>(h1, fwT2, fb2, h2, 512, 128, 1);
    fc_kernel<<<(16 * 10 + 3) / 4, 256, 0, stream>>>(h2, fwT3, fb3, out, 128, 10, 0);
}

// Round 16
// 817.545 us; speedup vs baseline: 1.1865x; 1.0973x over previous
//
#include <hip/hip_runtime.h>

#define BB 16
#define NN 1024
#define LDT 16384          // column count of all transposed feature buffers

typedef float4 f4;
typedef __attribute__((ext_vector_type(8))) short bf16x8;
typedef __attribute__((ext_vector_type(4))) float f32x4;

// bf16 pack/unpack (RNE)
__device__ __forceinline__ unsigned f2b1(float f) {
    unsigned u = __builtin_bit_cast(unsigned, f);
    return (u + 0x7fffu + ((u >> 16) & 1u)) >> 16;
}
__device__ __forceinline__ float b2f1(unsigned s) {
    unsigned u = (s & 0xffffu) << 16;
    return __builtin_bit_cast(float, u);
}

// LDS tile element offset, swizzled. Tile is [row][k] = [R][64] shorts.
// g = (row&7) ^ ((row>>3)&7): conflict-free for transpose-writes, row-copies and
// fragment reads, with compile-time register indexing everywhere.
#define SW(r, k) ((r) * 64 + ((k) ^ (((((r) & 7) ^ (((r) >> 3) & 7))) << 3)))

// ---- async global->LDS, 16B per lane. LDS dest = wave-uniform base + lane*16
// (linear); the global source chunk is pre-swizzled so data lands at SW(r,k):
// segment s covers rows 8s..8s+7; lane l -> row 8s+(l>>3), holds chunk
// jc = (l&7) ^ (l>>3) ^ (s&7) (== SW's placement). Reads stay unchanged.
__device__ __forceinline__ void gload16(const unsigned short* g, short* l) {
    __builtin_amdgcn_global_load_lds(
        (const __attribute__((address_space(1))) unsigned int*)g,
        (__attribute__((address_space(3))) unsigned int*)l, 16, 0, 0);
}

__device__ __forceinline__ float wave_sum(float v) {
    #pragma unroll
    for (int m = 32; m >= 1; m >>= 1) v += __shfl_xor(v, m);
    return v;
}
__device__ __forceinline__ float wave_max(float v) {
    #pragma unroll
    for (int m = 32; m >= 1; m >>= 1) v = fmaxf(v, __shfl_xor(v, m));
    return v;
}

// ---- transpose staging (pair-pack): T[r=0..127][c=0..63] = src[(c0+c)*LDT + col_base + r] ----
__device__ __forceinline__ void stage_tr(short* T, const unsigned short* src,
                                         size_t col_base, int c0, int Cvalid, int tid) {
    #pragma unroll
    for (int n = 0; n < 2; n++) {
        int q = n * 256 + tid;
        int p = q >> 4, h = q & 15;
        int cg = c0 + 2 * p;
        uint4 r0 = make_uint4(0, 0, 0, 0), r1 = make_uint4(0, 0, 0, 0);
        if (cg < Cvalid)     r0 = *(const uint4*)&src[(size_t)cg * LDT + col_base + 8 * h];
        if (cg + 1 < Cvalid) r1 = *(const uint4*)&src[(size_t)(cg + 1) * LDT + col_base + 8 * h];
        const unsigned* a0 = (const unsigned*)&r0;
        const unsigned* a1 = (const unsigned*)&r1;
        #pragma unroll
        for (int e = 0; e < 8; e++) {
            unsigned lo = (e & 1) ? (a0[e >> 1] >> 16) : (a0[e >> 1] & 0xffffu);
            unsigned hi = (e & 1) ? (a1[e >> 1] >> 16) : (a1[e >> 1] & 0xffffu);
            int r = 8 * h + e;
            *(unsigned*)&T[SW(r, 2 * p)] = lo | (hi << 16);
        }
    }
}

// ================= input prep =================
__global__ void xt_prep_kernel(const float* __restrict__ x, short* __restrict__ xh,
                               short* __restrict__ xl) {
    int m = blockIdx.x * 256 + threadIdx.x;
    #pragma unroll
    for (int c = 0; c < 8; c++) {
        float v = (c < 6) ? x[(size_t)m * 6 + c] : 0.f;
        unsigned h = f2b1(v);
        unsigned l = f2b1(v - b2f1(h));
        xh[(size_t)c * LDT + m] = (short)h;
        xl[(size_t)c * LDT + m] = (short)l;
    }
}

__global__ void wtt_prep_kernel(const float* __restrict__ Wk, short* __restrict__ WtT,
                                int Kp64, int KpValid, int CpadM1, int shift, int Cin, int Cout) {
    int idx = blockIdx.x * 256 + threadIdx.x;
    if (idx >= Cout * Kp64) return;
    int co = idx / Kp64, kk = idx - co * Kp64;
    int c = kk & CpadM1;
    float val = 0.f;
    if (kk < KpValid && c < Cin)
        val = Wk[((size_t)(kk >> shift) * Cin + c) * Cout + co];
    WtT[(size_t)co * Kp64 + kk] = (short)f2b1(val);
}

// ---- FC weight transpose: WtT[o][k] = Wt[k][o] ----
__global__ void wtrans_kernel(const float* __restrict__ Wt, float* __restrict__ WtT,
                              int K, int O) {
    int idx = blockIdx.x * 256 + threadIdx.x;
    if (idx >= K * O) return;
    int o = idx / K, k = idx - o * K;
    WtT[idx] = Wt[(size_t)k * O + o];
}

// ---- scaled copy: dst[c][m] = bf16( src[c][m] * coeff[m] ) ----
__global__ void scale_sc_kernel(const short* __restrict__ src, const float* __restrict__ coeff,
                                short* __restrict__ dst, int total8) {
    int q = blockIdx.x * 256 + threadIdx.x;
    if (q >= total8) return;
    size_t base = (size_t)q * 8;
    int m8 = (int)(base & (LDT - 1));
    uint4 v = *(const uint4*)&((const unsigned short*)src)[base];
    f4 c0 = *(const f4*)&coeff[m8];
    f4 c1 = *(const f4*)&coeff[m8 + 4];
    const float* cp0 = (const float*)&c0;
    const float* cp1 = (const float*)&c1;
    unsigned* vp = (unsigned*)&v;
    #pragma unroll
    for (int e = 0; e < 4; e++) {
        float se0 = (e < 2) ? cp0[2 * e] : cp1[2 * e - 4];
        float se1 = (e < 2) ? cp0[2 * e + 1] : cp1[2 * e - 3];
        vp[e] = f2b1(b2f1(vp[e]) * se0) | (f2b1(b2f1(vp[e] >> 16) * se1) << 16);
    }
    *(uint4*)&((unsigned short*)dst)[base] = v;
}

// ---- layer-wide transpose + fused per-point sqnorm partials ----
// XR[m][c] = XT[c][m] (rows padded/zeroed to CR); sqpart[cblk][m] = sum_c v^2
__global__ __launch_bounds__(256)
void xpose_kernel(const short* __restrict__ H, const short* __restrict__ L,
                  int Cvalid, int CR, short* __restrict__ XRh, short* __restrict__ XRl,
                  float* __restrict__ sqpart) {
    __shared__ short Th[128 * 64], Tl[128 * 64];
    int tid = threadIdx.x;
    int m0 = blockIdx.x * 128, c0 = blockIdx.y * 64;
    stage_tr(Th, (const unsigned short*)H, m0, c0, Cvalid, tid);
    stage_tr(Tl, (const unsigned short*)L, m0, c0, Cvalid, tid);
    __syncthreads();
    #pragma unroll
    for (int n = 0; n < 4; n++) {
        int q = n * 256 + tid;
        int r = q >> 3, j = q & 7;
        int g = (r & 7) ^ ((r >> 3) & 7);
        *(uint4*)&XRh[(size_t)(m0 + r) * CR + c0 + 8 * j] = *(const uint4*)&Th[r * 64 + 8 * (j ^ g)];
        *(uint4*)&XRl[(size_t)(m0 + r) * CR + c0 + 8 * j] = *(const uint4*)&Tl[r * 64 + 8 * (j ^ g)];
    }
    // fused sqnorm: 2 threads per point, 32 channels each, combine via shfl
    {
        int r = tid >> 1, half = tid & 1;
        const unsigned short* Thp = (const unsigned short*)Th;
        const unsigned short* Tlp = (const unsigned short*)Tl;
        float s = 0.f;
        #pragma unroll
        for (int k = 0; k < 32; k++) {
            int kk = half * 32 + k;
            float v = b2f1(Thp[SW(r, kk)]) + b2f1(Tlp[SW(r, kk)]);
            s += v * v;
        }
        s += __shfl_xor(s, 1);
        if (half == 0) sqpart[(size_t)blockIdx.y * LDT + m0 + r] = s;
    }
}

__global__ void sqt_red_kernel(const float* __restrict__ part, int NC, float* __restrict__ sq) {
    int m = blockIdx.x * 256 + threadIdx.x;
    float s = 0.f;
    for (int y = 0; y < NC; y++) s += part[(size_t)y * LDT + m];
    sq[m] = s;
}

// ====== adjacency + fused row-sum partials: W[b][j][i] = exp(2G - sq_i - sq_j) ======
// 4 waves; wave tile 64(j) x 64(i). Staging via global_load_lds from row-major XR.
// Off-diag partial sums -> Wpart; diag -> diagW.
__global__ __launch_bounds__(256)
void adj_mfma_kernel(const short* __restrict__ XRh, const short* __restrict__ XRl,
                     int ck64, int CR, const float* __restrict__ sq,
                     short* __restrict__ Wb, float* __restrict__ Wpart,
                     float* __restrict__ diagW) {
    __shared__ short Ah[128 * 64], Al[128 * 64], Bh[128 * 64], Bl[128 * 64];
    __shared__ float jpart[128][2];
    int tid = threadIdx.x, lane = tid & 63, w = tid >> 6;
    int wj = w >> 1, wi = w & 1;
    int b = blockIdx.z, i0 = blockIdx.x * 128, j0 = blockIdx.y * 128;
    size_t bo = (size_t)b * NN;
    f32x4 acc[4][4] = {};
    const unsigned short* Hp = (const unsigned short*)XRh;
    const unsigned short* Lp = (const unsigned short*)XRl;
    // per-lane pre-swizzled source offsets for the 4 segments this wave stages per tile
    int rr = lane >> 3, jj = lane & 7;
    size_t offI[4], offJ[4];
    #pragma unroll
    for (int m = 0; m < 4; m++) {
        int s = w + m * 4;
        int jc = jj ^ rr ^ (s & 7);
        offI[m] = (size_t)(bo + i0 + 8 * s + rr) * CR + 8 * jc;
        offJ[m] = (size_t)(bo + j0 + 8 * s + rr) * CR + 8 * jc;
    }
    for (int t = 0; t < ck64; t++) {
        int c0 = t * 64;
        #pragma unroll
        for (int m = 0; m < 4; m++) {
            int s512 = (w + m * 4) * 512;
            gload16(Hp + offI[m] + c0, Ah + s512);
            gload16(Lp + offI[m] + c0, Al + s512);
            gload16(Hp + offJ[m] + c0, Bh + s512);
            gload16(Lp + offJ[m] + c0, Bl + s512);
        }
        __syncthreads();
        int la = lane & 15;
        #pragma unroll
        for (int ks = 0; ks < 2; ks++) {
            int kb = ks * 32 + (lane >> 4) * 8;
            bf16x8 jh[4], jl[4], ih[4], il[4];
            #pragma unroll
            for (int f = 0; f < 4; f++) {
                int jr = wj * 64 + f * 16 + la;
                jh[f] = *(const bf16x8*)&Bh[SW(jr, kb)];
                jl[f] = *(const bf16x8*)&Bl[SW(jr, kb)];
                int ir = wi * 64 + f * 16 + la;
                ih[f] = *(const bf16x8*)&Ah[SW(ir, kb)];
                il[f] = *(const bf16x8*)&Al[SW(ir, kb)];
            }
            #pragma unroll
            for (int fq = 0; fq < 4; fq++)
                #pragma unroll
                for (int fi = 0; fi < 4; fi++) {
                    acc[fq][fi] = __builtin_amdgcn_mfma_f32_16x16x32_bf16(jh[fq], ih[fi], acc[fq][fi], 0, 0, 0);
                    acc[fq][fi] = __builtin_amdgcn_mfma_f32_16x16x32_bf16(jh[fq], il[fi], acc[fq][fi], 0, 0, 0);
                    acc[fq][fi] = __builtin_amdgcn_mfma_f32_16x16x32_bf16(jl[fq], ih[fi], acc[fq][fi], 0, 0, 0);
                }
        }
        __syncthreads();
    }
    const float* sqb = sq + bo;
    unsigned short* Wout = (unsigned short*)Wb + bo * NN;
    float si_[4];
    int iloc[4];
    #pragma unroll
    for (int fi = 0; fi < 4; fi++) {
        iloc[fi] = i0 + wi * 64 + fi * 16 + (lane & 15);
        si_[fi] = sqb[iloc[fi]];
    }
    #pragma unroll
    for (int fq = 0; fq < 4; fq++) {
        int jb = j0 + wj * 64 + fq * 16 + (lane >> 4) * 4;
        #pragma unroll
        for (int r = 0; r < 4; r++) {
            int j = jb + r;
            float sj = sqb[j];
            float p = 0.f;
            #pragma unroll
            for (int fi = 0; fi < 4; fi++) {
                float val = __expf(2.f * ((const float*)&acc[fq][fi])[r] - si_[fi] - sj);
                Wout[(size_t)j * NN + iloc[fi]] = (unsigned short)f2b1(val);
                if (iloc[fi] == j) diagW[bo + j] = val;
                else p += val;
            }
            p += __shfl_xor(p, 1); p += __shfl_xor(p, 2);
            p += __shfl_xor(p, 4); p += __shfl_xor(p, 8);
            if ((lane & 15) == 0)
                jpart[wj * 64 + fq * 16 + (lane >> 4) * 4 + r][wi] = p;
        }
    }
    __syncthreads();
    if (tid < 128)
        Wpart[(size_t)blockIdx.x * (BB * NN) + bo + j0 + tid] = jpart[tid][0] + jpart[tid][1];
}

// ====== reduce partials -> coefficient vectors ======
__global__ void reduce_prep_kernel(const float* __restrict__ Wpart, const float* __restrict__ diagW,
                                   float* dinv, float* dinvP, float* cA1, float* cA2, float* cAV) {
    int idx = blockIdx.x * 256 + threadIdx.x;    // [0, 16384)
    float s = 0.f;
    #pragma unroll
    for (int x = 0; x < 8; x++) s += Wpart[(size_t)x * (BB * NN) + idx];
    float d = diagW[idx];
    float dv = rsqrtf(s + d);    // full sum (incl diag)
    float dp = rsqrtf(s);        // exact off-diag sum (no cancellation)
    dinv[idx] = dv; dinvP[idx] = dp;
    cA1[idx] = -dv; cA2[idx] = -2.f * dv; cAV[idx] = -dp;
}

// ====== W-GEMM (8 waves): Dst[c][i] = cA_i * sum_j W[i][j]*Bsc[c][j] (+ prevSign*Prev[c][i]) ======
// Double-buffered LDS, single barrier per k-tile: STAGE(t+1) issues before tile-t
// MFMAs so load latency hides under compute (guide T3/T4 minimum-2-phase recipe).
// XB = i-tile rows (128 or 64). Per-element math identical to the 2-barrier version.
template<bool HAS_PREV, bool SKIP_DIAG, bool WRITE_SC, int XB>
__global__ __launch_bounds__(512)
void wgemm2_kernel(const short* __restrict__ W, const short* __restrict__ Bsc,
                   const float* __restrict__ cAvec, float prevSign,
                   const short* __restrict__ PrevT, const float* __restrict__ scVec,
                   short* __restrict__ DstT, short* __restrict__ DstSc, int Cvalid) {
    __shared__ short As[2][XB * 64], Bs[2][128 * 64];
    constexpr int NFI = XB / 64;                 // i-frags per wave (2 or 1)
    int tid = threadIdx.x, lane = tid & 63, w = tid >> 6;
    int wcc = w >> 2, wii = w & 3;               // wave tile: 64 c x XB/4 i
    int b = blockIdx.z, i0 = blockIdx.x * XB, c0 = blockIdx.y * 128;
    size_t bo = (size_t)b * NN;
    const unsigned short* Wp = (const unsigned short*)W + bo * NN;
    const unsigned short* Bp = (const unsigned short*)Bsc;
    int rr = lane >> 3, jj = lane & 7;
    int jc = jj ^ rr ^ (w & 7);                  // (w+8)&7 == w&7
    const unsigned short* aR0 = Wp + (size_t)(i0 + 8 * w + rr) * NN + 8 * jc;
    const unsigned short* aR1 = Wp + (size_t)(i0 + 8 * ((XB == 128) ? w + 8 : w) + rr) * NN + 8 * jc;
    const unsigned short* bR0 = Bp + (size_t)(c0 + 8 * w + rr) * LDT + bo + 8 * jc;
    const unsigned short* bR1 = Bp + (size_t)(c0 + 8 * (w + 8) + rr) * LDT + bo + 8 * jc;
    int aO0 = w * 512;
    int aO1 = ((XB == 128) ? w + 8 : w) * 512;
    int bO0 = w * 512, bO1 = (w + 8) * 512;
    auto STAGE = [&](int k0, int buf) {
        gload16(aR0 + k0, As[buf] + aO0);
        if (XB == 128) gload16(aR1 + k0, As[buf] + aO1);
        gload16(bR0 + k0, Bs[buf] + bO0);
        gload16(bR1 + k0, Bs[buf] + bO1);
    };
    f32x4 acc[4][NFI] = {};
    STAGE(0, 0);
    __syncthreads();                              // drains vmcnt; tile 0 published
    int cur = 0;
    for (int t = 0; t < NN / 64; t++) {
        int k0 = t * 64;
        bool more = (t + 1 < NN / 64);
        if (more) STAGE(k0 + 64, cur ^ 1);        // prefetch next tile (other buffer)
        if (SKIP_DIAG) {
            if (k0 >= i0 && k0 < i0 + XB) {       // diag band intersects this k-tile
                if (tid < 64) As[cur][SW((k0 - i0) + tid, tid)] = 0;
                __syncthreads();                  // publish patch (rare, block-uniform)
            }
        }
        int la = lane & 15;
        #pragma unroll
        for (int ks = 0; ks < 2; ks++) {
            int kb = ks * 32 + (lane >> 4) * 8;
            bf16x8 ac[4], bi[NFI];
            #pragma unroll
            for (int f = 0; f < 4; f++) ac[f] = *(const bf16x8*)&Bs[cur][SW(wcc * 64 + f * 16 + la, kb)];
            #pragma unroll
            for (int f = 0; f < NFI; f++) bi[f] = *(const bf16x8*)&As[cur][SW(wii * (XB / 4) + f * 16 + la, kb)];
            #pragma unroll
            for (int fq = 0; fq < 4; fq++)
                #pragma unroll
                for (int fi = 0; fi < NFI; fi++)
                    acc[fq][fi] = __builtin_amdgcn_mfma_f32_16x16x32_bf16(ac[fq], bi[fi], acc[fq][fi], 0, 0, 0);
        }
        if (more) __syncthreads();                // joins readers of cur; drains next stage
        cur ^= 1;
    }
    const unsigned short* Pp = (const unsigned short*)PrevT;
    unsigned short* Dp = (unsigned short*)DstT;
    unsigned short* Sp = (unsigned short*)DstSc;
    #pragma unroll
    for (int fi = 0; fi < NFI; fi++) {
        int i = i0 + wii * (XB / 4) + fi * 16 + (lane & 15);
        float ca = cAvec[bo + i];
        float sc = WRITE_SC ? scVec[bo + i] : 0.f;
        #pragma unroll
        for (int fq = 0; fq < 4; fq++) {
            int cb = c0 + wcc * 64 + fq * 16 + (lane >> 4) * 4;
            const float* av = (const float*)&acc[fq][fi];
            #pragma unroll
            for (int r = 0; r < 4; r++) {
                int c = cb + r;
                if (c < Cvalid) {
                    float v = ca * av[r];
                    if (HAS_PREV) v += prevSign * b2f1(Pp[(size_t)c * LDT + bo + i]);
                    Dp[(size_t)c * LDT + bo + i] = (unsigned short)f2b1(v);
                    if (WRITE_SC) Sp[(size_t)c * LDT + bo + i] = (unsigned short)f2b1(v * sc);
                }
            }
        }
    }
}

// ====== feature GEMM (8 waves): Out[co][m] = relu(sum_kk Zcat[m][kk]*Wt[kk][co] + bias) ======
// Double-buffered LDS, single barrier per k-tile: loadA(t+1)+gloadB(t+1) issue
// before tile-t MFMAs; unpack(t+1) lands in the idle buffer after MFMAs.
__global__ __launch_bounds__(512)
void fgemm_mfma_kernel(const short* __restrict__ A0T, const short* __restrict__ ZrT,
                       const short* __restrict__ WtT, int Kp64, int KpValid, int Cpad,
                       const float* __restrict__ bias,
                       short* __restrict__ OutH, short* __restrict__ OutL) {
    __shared__ short As[2][128 * 64], Bs[2][128 * 64];
    int tid = threadIdx.x, lane = tid & 63, w = tid >> 6;
    int wco = w >> 2, wm = w & 3;                // wave tile: 64 co x 32 m
    int m0 = blockIdx.x * 128, co0 = blockIdx.y * 128;
    const unsigned short* A0 = (const unsigned short*)A0T;
    const unsigned short* Zr = (const unsigned short*)ZrT;
    const unsigned short* Wt = (const unsigned short*)WtT;
    // B staging addresses (gload16, row stride Kp64)
    int rr = lane >> 3, jj = lane & 7;
    int jcB = jj ^ rr ^ (w & 7);
    const unsigned short* bB0 = Wt + (size_t)(co0 + 8 * w + rr) * Kp64 + 8 * jcB;
    const unsigned short* bB1 = Wt + (size_t)(co0 + 8 * (w + 8) + rr) * Kp64 + 8 * jcB;
    int bO0 = w * 512, bO1 = (w + 8) * 512;
    int p = tid >> 4, h = tid & 15;
    uint4 ra0, ra1;
    auto loadA = [&](int kk0) {
        int kg0 = kk0 + 2 * p;
        ra0 = make_uint4(0, 0, 0, 0); ra1 = make_uint4(0, 0, 0, 0);
        if (kg0 < KpValid) {
            const unsigned short* s0 = (kg0 < Cpad) ? (A0 + (size_t)kg0 * LDT)
                                                    : (Zr + (size_t)(kg0 - Cpad) * LDT);
            ra0 = *(const uint4*)&s0[m0 + 8 * h];
        }
        if (kg0 + 1 < KpValid) {
            int kg1 = kg0 + 1;
            const unsigned short* s1 = (kg1 < Cpad) ? (A0 + (size_t)kg1 * LDT)
                                                    : (Zr + (size_t)(kg1 - Cpad) * LDT);
            ra1 = *(const uint4*)&s1[m0 + 8 * h];
        }
    };
    auto unpackA = [&](int buf) {                // held A regs -> LDS, static e indexing
        const unsigned* a0 = (const unsigned*)&ra0;
        const unsigned* a1 = (const unsigned*)&ra1;
        #pragma unroll
        for (int e = 0; e < 8; e++) {
            unsigned lo = (e & 1) ? (a0[e >> 1] >> 16) : (a0[e >> 1] & 0xffffu);
            unsigned hi = (e & 1) ? (a1[e >> 1] >> 16) : (a1[e >> 1] & 0xffffu);
            *(unsigned*)&As[buf][SW(8 * h + e, 2 * p)] = lo | (hi << 16);
        }
    };
    f32x4 acc[4][2] = {};
    loadA(0);
    gload16(bB0, Bs[0] + bO0);
    gload16(bB1, Bs[0] + bO1);
    unpackA(0);
    __syncthreads();                              // drains B0; publishes As[0]
    int cur = 0;
    for (int kk0 = 0; kk0 < Kp64; kk0 += 64) {
        bool more = (kk0 + 64 < Kp64);
        if (more) {
            loadA(kk0 + 64);                      // issue next A reg loads
            gload16(bB0 + kk0 + 64, Bs[cur ^ 1] + bO0);   // next B -> other buffer
            gload16(bB1 + kk0 + 64, Bs[cur ^ 1] + bO1);
        }
        int la = lane & 15;
        #pragma unroll
        for (int ks = 0; ks < 2; ks++) {
            int kb = ks * 32 + (lane >> 4) * 8;
            bf16x8 ac[4], bm[2];
            #pragma unroll
            for (int f = 0; f < 4; f++) ac[f] = *(const bf16x8*)&Bs[cur][SW(wco * 64 + f * 16 + la, kb)];
            #pragma unroll
            for (int f = 0; f < 2; f++) bm[f] = *(const bf16x8*)&As[cur][SW(wm * 32 + f * 16 + la, kb)];
            #pragma unroll
            for (int fq = 0; fq < 4; fq++)
                #pragma unroll
                for (int fi = 0; fi < 2; fi++)
                    acc[fq][fi] = __builtin_amdgcn_mfma_f32_16x16x32_bf16(ac[fq], bm[fi], acc[fq][fi], 0, 0, 0);
        }
        if (more) {
            unpackA(cur ^ 1);                     // next A -> other buffer (regs arrived under MFMAs)
            __syncthreads();                      // joins readers of cur; drains next B stage
        }
        cur ^= 1;
    }
    unsigned short* OH = (unsigned short*)OutH;
    unsigned short* OL = (unsigned short*)OutL;
    #pragma unroll
    for (int fi = 0; fi < 2; fi++) {
        int m = m0 + wm * 32 + fi * 16 + (lane & 15);
        #pragma unroll
        for (int fq = 0; fq < 4; fq++) {
            int cb = co0 + wco * 64 + fq * 16 + (lane >> 4) * 4;
            const float* av = (const float*)&acc[fq][fi];
            #pragma unroll
            for (int r = 0; r < 4; r++) {
                int co = cb + r;
                float v = av[r] + bias[co];
                v = v > 0.f ? v : 0.f;
                unsigned ph = f2b1(v);
                unsigned pl = f2b1(v - b2f1(ph));
                OH[(size_t)co * LDT + m] = (unsigned short)ph;
                OL[(size_t)co * LDT + m] = (unsigned short)pl;
            }
        }
    }
}

// ====== M partials: Mpart[z][cj][ci] = sum_{m in chunk} XT[ci][m]*VT[cj][m] ======
// 2-phase double-buffer (LDS 64 KB; residency stays 2 blocks/CU at grid>=512).
__global__ __launch_bounds__(256)
void mgemm_mfma_kernel(const short* __restrict__ XT, const short* __restrict__ VT,
                       float* __restrict__ Mpart, int Cout, int kChunk) {
    __shared__ short As[2][128 * 64], Bs[2][128 * 64];
    int tid = threadIdx.x, lane = tid & 63, w = tid >> 6;
    int wcj = w >> 1, wci = w & 1;
    int ci0 = blockIdx.x * 128, cj0 = blockIdx.y * 128;
    int kStart = blockIdx.z * kChunk;
    const unsigned short* Xp = (const unsigned short*)XT + (size_t)ci0 * LDT;
    const unsigned short* Vp = (const unsigned short*)VT + (size_t)cj0 * LDT;
    // hoisted per-lane source addresses: 4 waves x 4 segments each
    int rr = lane >> 3, jj = lane & 7;
    const unsigned short* aB[4];
    const unsigned short* bB[4];
    int sO[4];
    #pragma unroll
    for (int n = 0; n < 4; n++) {
        int s = w + n * 4;
        int jc = jj ^ rr ^ (s & 7);
        aB[n] = Xp + (size_t)(8 * s + rr) * LDT + 8 * jc;
        bB[n] = Vp + (size_t)(8 * s + rr) * LDT + 8 * jc;
        sO[n] = s * 512;
    }
    auto STAGE = [&](int k0, int buf) {
        #pragma unroll
        for (int n = 0; n < 4; n++) {
            gload16(aB[n] + k0, As[buf] + sO[n]);
            gload16(bB[n] + k0, Bs[buf] + sO[n]);
        }
    };
    f32x4 acc[4][4] = {};
    STAGE(kStart, 0);
    __syncthreads();
    int cur = 0;
    int nt = kChunk / 64;
    for (int t = 0; t < nt; t++) {
        int k0 = kStart + t * 64;
        bool more = (t + 1 < nt);
        if (more) STAGE(k0 + 64, cur ^ 1);
        int la = lane & 15;
        #pragma unroll
        for (int ks = 0; ks < 2; ks++) {
            int kb = ks * 32 + (lane >> 4) * 8;
            bf16x8 aj[4], bi[4];
            #pragma unroll
            for (int f = 0; f < 4; f++) {
                aj[f] = *(const bf16x8*)&Bs[cur][SW(wcj * 64 + f * 16 + la, kb)];   // cj frags
                bi[f] = *(const bf16x8*)&As[cur][SW(wci * 64 + f * 16 + la, kb)];   // ci frags
            }
            #pragma unroll
            for (int fq = 0; fq < 4; fq++)
                #pragma unroll
                for (int fi = 0; fi < 4; fi++)
                    acc[fq][fi] = __builtin_amdgcn_mfma_f32_16x16x32_bf16(aj[fq], bi[fi], acc[fq][fi], 0, 0, 0);
        }
        if (more) __syncthreads();
        cur ^= 1;
    }
    float* pt = Mpart + (size_t)blockIdx.z * Cout * Cout;
    #pragma unroll
    for (int fq = 0; fq < 4; fq++) {
        int cjb = cj0 + wcj * 64 + fq * 16 + (lane >> 4) * 4;
        #pragma unroll
        for (int fi = 0; fi < 4; fi++) {
            int ci = ci0 + wci * 64 + fi * 16 + (lane & 15);
            const float* av = (const float*)&acc[fq][fi];
            #pragma unroll
            for (int r = 0; r < 4; r++)
                pt[(size_t)(cjb + r) * Cout + ci] = av[r];
        }
    }
}

// ================= Frobenius norm of summed split-K partials (deterministic) =================
__global__ void fro1_kernel(const float* __restrict__ part, int nElem, int splitk,
                            float* __restrict__ blockSS) {
    int tid = threadIdx.x;
    float ss = 0.f;
    for (int idx = blockIdx.x * 256 + tid; idx < nElem; idx += 1024 * 256) {
        float s = 0.f;
        for (int z = 0; z < splitk; z++) s += part[(size_t)z * nElem + idx];
        ss += s * s;
    }
    __shared__ float red[256];
    red[tid] = ss; __syncthreads();
    for (int m = 128; m >= 1; m >>= 1) { if (tid < m) red[tid] += red[tid + m]; __syncthreads(); }
    if (tid == 0) blockSS[blockIdx.x] = red[0];
}
__global__ void fro2_kernel(const float* __restrict__ blockSS, float* __restrict__ outp) {
    int tid = threadIdx.x;
    float s = 0.f;
    for (int i = tid; i < 1024; i += 256) s += blockSS[i];
    __shared__ float red[256];
    red[tid] = s; __syncthreads();
    for (int m = 128; m >= 1; m >>= 1) { if (tid < m) red[tid] += red[tid + m]; __syncthreads(); }
    if (tid == 0) *outp = sqrtf(red[0]);
}

// ================= max-pool over points: one wave per (b,co) row, coalesced =================
__global__ void pool_kernel(const short* __restrict__ H, const short* __restrict__ L,
                            float* __restrict__ out) {
    int wave = threadIdx.x >> 6, lane = threadIdx.x & 63;
    int r = blockIdx.x * 4 + wave;             // [0, 16384): r = co*16 + b
    int co = r >> 4, b = r & 15;
    const unsigned short* h = (const unsigned short*)H + (size_t)co * LDT + b * NN;
    const unsigned short* l = (const unsigned short*)L + (size_t)co * LDT + b * NN;
    float m = -1e30f;
    #pragma unroll
    for (int it = 0; it < 2; it++) {
        int n8 = (it * 64 + lane) * 8;
        uint4 vh = *(const uint4*)&h[n8];
        uint4 vl = *(const uint4*)&l[n8];
        const unsigned* hp = (const unsigned*)&vh;
        const unsigned* lp = (const unsigned*)&vl;
        #pragma unroll
        for (int e = 0; e < 4; e++) {
            m = fmaxf(m, b2f1(hp[e]) + b2f1(lp[e]));
            m = fmaxf(m, b2f1(hp[e] >> 16) + b2f1(lp[e] >> 16));
        }
    }
    m = wave_max(m);
    if (lane == 0) out[b * 1024 + co] = m;
}

// ================= small FC: one wave per (b,o) output, lanes stride K (coalesced) =================
__global__ void fc_kernel(const float* __restrict__ in, const float* __restrict__ WtT,
                          const float* __restrict__ bias, float* __restrict__ out,
                          int K, int O, int doRelu) {
    int wave = threadIdx.x >> 6, lane = threadIdx.x & 63;
    int idx = blockIdx.x * 4 + wave;           // [0, 16*O)
    if (idx >= 16 * O) return;
    int b = idx / O, o = idx - b * O;
    const float* ib = in + (size_t)b * K;
    const float* wr = WtT + (size_t)o * K;
    float s = 0.f;
    for (int k = lane * 4; k < K; k += 256) {
        f4 a = *(const f4*)&ib[k];
        f4 wv = *(const f4*)&wr[k];
        s += a.x * wv.x + a.y * wv.y + a.z * wv.z + a.w * wv.w;
    }
    s = wave_sum(s);
    if (lane == 0) {
        s += bias[o];
        if (doRelu) s = fmaxf(s, 0.f);
        out[(size_t)b * O + o] = s;
    }
}

extern "C" void kernel_launch(void* const* d_in, const int* in_sizes, int n_in,
                              void* d_out, int out_size, void* d_ws, size_t ws_size,
                              hipStream_t stream) {
    const float* x   = (const float*)d_in[0];
    const float* w1  = (const float*)d_in[4];
    const float* b1  = (const float*)d_in[5];
    const float* w2  = (const float*)d_in[6];
    const float* b2  = (const float*)d_in[7];
    const float* w3  = (const float*)d_in[8];
    const float* b3  = (const float*)d_in[9];
    const float* fw1 = (const float*)d_in[10];
    const float* fb1 = (const float*)d_in[11];
    const float* fw2 = (const float*)d_in[12];
    const float* fb2 = (const float*)d_in[13];
    const float* fw3 = (const float*)d_in[14];
    const float* fb3 = (const float*)d_in[15];
    float* out = (float*)d_out;

    char* ws = (char*)d_ws;
    size_t off = 0;
    auto alloc = [&](size_t bytes) -> void* {
        void* p = ws + off; off += (bytes + 255) & ~(size_t)255; return p;
    };
    short* Wbuf = (short*)alloc((size_t)BB * NN * NN * 2);   // 32 MiB; Mpart aliases after V-step
    short* Zbuf = (short*)alloc((size_t)1024 * LDT * 2);     // 32 MiB raw Z slices; V output later
    short* ZSc  = (short*)alloc((size_t)1024 * LDT * 2);     // 32 MiB scaled Z slices / scaled Out (V)
    short* Z0Sc = (short*)alloc((size_t)512 * LDT * 2);      // 16 MiB scaled Z0 (first wgemm B)
    short* XRh  = (short*)alloc((size_t)512 * LDT * 2);      // 16 MiB row-major X (hi)
    short* XRl  = (short*)alloc((size_t)512 * LDT * 2);      // 16 MiB row-major X (lo)
    short* o1H  = (short*)alloc((size_t)128 * LDT * 2);
    short* o1L  = (short*)alloc((size_t)128 * LDT * 2);
    short* o2H  = (short*)alloc((size_t)512 * LDT * 2);
    short* o2L  = (short*)alloc((size_t)512 * LDT * 2);
    short* o3H  = (short*)alloc((size_t)1024 * LDT * 2);
    short* o3L  = (short*)alloc((size_t)1024 * LDT * 2);
    short* xTh  = (short*)alloc((size_t)8 * LDT * 2);
    short* xTl  = (short*)alloc((size_t)8 * LDT * 2);
    short* WtT  = (short*)alloc((size_t)1024 * 1536 * 2);
    float* fwT1 = (float*)alloc((size_t)512 * 1024 * 4);
    float* fwT2 = (float*)alloc((size_t)128 * 512 * 4);
    float* fwT3 = (float*)alloc((size_t)10 * 128 * 4);
    float* sqpart = (float*)alloc((size_t)8 * LDT * 4);
    float* Wpart  = (float*)alloc((size_t)8 * BB * NN * 4);
    float* diagW  = (float*)alloc(BB * NN * 4);
    float* sq    = (float*)alloc(BB * NN * 4);
    float* dinv  = (float*)alloc(BB * NN * 4);
    float* dinvP = (float*)alloc(BB * NN * 4);
    float* cA1   = (float*)alloc(BB * NN * 4);
    float* cA2   = (float*)alloc(BB * NN * 4);
    float* cAV   = (float*)alloc(BB * NN * 4);
    float* pooled= (float*)alloc(BB * 1024 * 4);
    float* h1    = (float*)alloc(BB * 512 * 4);
    float* h2    = (float*)alloc(BB * 128 * 4);
    float* blockSS = (float*)alloc(1024 * 4);
    float* Mpart = (float*)Wbuf;      // alias: W dead after V-step
    (void)ws_size; (void)in_sizes; (void)n_in; (void)out_size;

    struct Layer {
        const short *XTh, *XTl;       // input features (transposed hi/lo)
        int C, K, Cpad, shift, Kp64, KpValid, Cout, splitk, rIdx;
        const float *Wk, *bk;
        short *OutH, *OutL;
    };
    Layer L[3] = {
        { xTh, xTl, 8,   6, 8,   3, 64,   48,   128,  64, 160, w1, b1, o1H, o1L },
        { o1H, o1L, 128, 5, 128, 7, 640,  640,  512,  32, 161, w2, b2, o2H, o2L },
        { o2H, o2L, 512, 3, 512, 9, 1536, 1536, 1024, 8,  162, w3, b3, o3H, o3L },
    };

    xt_prep_kernel<<<LDT / 256, 256, 0, stream>>>(x, xTh, xTl);
    wtrans_kernel<<<(1024 * 512 + 255) / 256, 256, 0, stream>>>(fw1, fwT1, 1024, 512);
    wtrans_kernel<<<(512 * 128 + 255) / 256, 256, 0, stream>>>(fw2, fwT2, 512, 128);
    wtrans_kernel<<<(128 * 10 + 255) / 256, 256, 0, stream>>>(fw3, fwT3, 128, 10);

    for (int l = 0; l < 3; l++) {
        const Layer& P = L[l];
        int CR = (P.Cpad < 64) ? 64 : P.Cpad;    // row-major stride (zero-padded)
        wtt_prep_kernel<<<(P.Cout * P.Kp64 + 255) / 256, 256, 0, stream>>>(
            P.Wk, WtT, P.Kp64, P.KpValid, P.Cpad - 1, P.shift, (l == 0) ? 6 : P.C, P.Cout);
        // once-per-layer transpose to row-major [point][CR], fused sqnorm partials
        xpose_kernel<<<dim3(LDT / 128, CR / 64), 256, 0, stream>>>(
            P.XTh, P.XTl, P.Cpad, CR, XRh, XRl, sqpart);
        sqt_red_kernel<<<LDT / 256, 256, 0, stream>>>(sqpart, CR / 64, sq);
        adj_mfma_kernel<<<dim3(8, 8, BB), 256, 0, stream>>>(XRh, XRl, CR / 64, CR, sq,
                                                            Wbuf, Wpart, diagW);
        reduce_prep_kernel<<<BB * NN / 256, 256, 0, stream>>>(Wpart, diagW, dinv, dinvP, cA1, cA2, cAV);

        // scaled Z0 for the first wgemm's B operand
        scale_sc_kernel<<<(P.Cpad * LDT / 8 + 255) / 256, 256, 0, stream>>>(
            P.XTh, dinv, Z0Sc, P.Cpad * LDT / 8);

        int cT = (P.Cpad + 127) / 128;
        bool sm = (P.Cpad <= 128);               // small-C: 64-row i-tiles, 2x grid
        auto sliceR = [&](int k) -> short* { return Zbuf + (size_t)(k - 1) * P.Cpad * LDT; };
        auto sliceS = [&](int k) -> short* { return ZSc  + (size_t)(k - 1) * P.Cpad * LDT; };
        // Z1 = -dinv .* (W @ Z0sc)
        if (P.K > 2) {
            if (sm) wgemm2_kernel<false, false, true, 64><<<dim3(NN / 64, cT, BB), 512, 0, stream>>>(
                        Wbuf, Z0Sc, cA1, 0.f, (const short*)nullptr, dinv, sliceR(1), sliceS(1), P.Cpad);
            else    wgemm2_kernel<false, false, true, 128><<<dim3(NN / 128, cT, BB), 512, 0, stream>>>(
                        Wbuf, Z0Sc, cA1, 0.f, (const short*)nullptr, dinv, sliceR(1), sliceS(1), P.Cpad);
        } else {
            if (sm) wgemm2_kernel<false, false, false, 64><<<dim3(NN / 64, cT, BB), 512, 0, stream>>>(
                        Wbuf, Z0Sc, cA1, 0.f, (const short*)nullptr, dinv, sliceR(1), (short*)nullptr, P.Cpad);
            else    wgemm2_kernel<false, false, false, 128><<<dim3(NN / 128, cT, BB), 512, 0, stream>>>(
                        Wbuf, Z0Sc, cA1, 0.f, (const short*)nullptr, dinv, sliceR(1), (short*)nullptr, P.Cpad);
        }
        // Zk = -2*dinv .* (W @ Zsc_{k-1}) - Z_{k-2}
        for (int k = 2; k < P.K; k++) {
            const short* prevT = (k == 2) ? P.XTh : sliceR(k - 2);
            if (k < P.K - 1) {
                if (sm) wgemm2_kernel<true, false, true, 64><<<dim3(NN / 64, cT, BB), 512, 0, stream>>>(
                            Wbuf, sliceS(k - 1), cA2, -1.f, prevT, dinv, sliceR(k), sliceS(k), P.Cpad);
                else    wgemm2_kernel<true, false, true, 128><<<dim3(NN / 128, cT, BB), 512, 0, stream>>>(
                            Wbuf, sliceS(k - 1), cA2, -1.f, prevT, dinv, sliceR(k), sliceS(k), P.Cpad);
            } else {
                if (sm) wgemm2_kernel<true, false, false, 64><<<dim3(NN / 64, cT, BB), 512, 0, stream>>>(
                            Wbuf, sliceS(k - 1), cA2, -1.f, prevT, dinv, sliceR(k), (short*)nullptr, P.Cpad);
                else    wgemm2_kernel<true, false, false, 128><<<dim3(NN / 128, cT, BB), 512, 0, stream>>>(
                            Wbuf, sliceS(k - 1), cA2, -1.f, prevT, dinv, sliceR(k), (short*)nullptr, P.Cpad);
            }
        }
        fgemm_mfma_kernel<<<dim3(LDT / 128, P.Cout / 128), 512, 0, stream>>>(
            P.XTh, Zbuf, WtT, P.Kp64, P.KpValid, P.Cpad, P.bk, P.OutH, P.OutL);
        // V = out - dinvP .* (W_nodiag @ (dinvP .* out)); scaled out -> ZSc, V -> Zbuf
        scale_sc_kernel<<<(P.Cout * LDT / 8 + 255) / 256, 256, 0, stream>>>(
            P.OutH, dinvP, ZSc, P.Cout * LDT / 8);
        int cTV = P.Cout / 128;
        if (P.Cout <= 128)
            wgemm2_kernel<true, true, false, 64><<<dim3(NN / 64, cTV, BB), 512, 0, stream>>>(
                Wbuf, ZSc, cAV, 1.f, P.OutH, dinvP, Zbuf, (short*)nullptr, P.Cout);
        else
            wgemm2_kernel<true, true, false, 128><<<dim3(NN / 128, cTV, BB), 512, 0, stream>>>(
                Wbuf, ZSc, cAV, 1.f, P.OutH, dinvP, Zbuf, (short*)nullptr, P.Cout);
        int kChunk = LDT / P.splitk;
        mgemm_mfma_kernel<<<dim3(P.Cout / 128, P.Cout / 128, P.splitk), 256, 0, stream>>>(
            P.OutH, Zbuf, Mpart, P.Cout, kChunk);
        fro1_kernel<<<1024, 256, 0, stream>>>(Mpart, P.Cout * P.Cout, P.splitk, blockSS);
        fro2_kernel<<<1, 256, 0, stream>>>(blockSS, out + P.rIdx);
    }
    pool_kernel<<<16384 / 4, 256, 0, stream>>>(o3H, o3L, pooled);
    fc_kernel<<<(16 * 512 + 3) / 4, 256, 0, stream>>>(pooled, fwT1, fb1, h1, 1024, 512, 1);
    fc_kernel<<<(16 * 128 + 3) / 4, 256, 0, stream>>>(h1, fwT2, fb2, h2, 512, 128, 1);
    fc_kernel<<<(16 * 10 + 3) / 4, 256, 0, stream>>>(h2, fwT3, fb3, out, 128, 10, 0);
}